// Round 5
// baseline (149.141 us; speedup 1.0000x reference)
//
#include <hip/hip_runtime.h>
#include <hip/hip_bf16.h>
#include <math.h>

#define BB 16
#define TT 64
#define HWXY 512
#define EE 256
#define VV 128

typedef __bf16 bf16x8 __attribute__((ext_vector_type(8)));
typedef unsigned short u16x8 __attribute__((ext_vector_type(8)));
typedef float f32x4 __attribute__((ext_vector_type(4)));

__device__ __forceinline__ f32x4 mfma16(bf16x8 a, bf16x8 b, f32x4 c) {
    return __builtin_amdgcn_mfma_f32_16x16x32_bf16(a, b, c, 0, 0, 0);
}

__device__ __forceinline__ bf16x8 bc(u16x8 v) { return __builtin_bit_cast(bf16x8, v); }

__device__ __forceinline__ unsigned short f2bf(float f) {
    union { float f; unsigned int i; } v; v.f = f;
    unsigned int x = v.i;
    return (unsigned short)((x + 0x7fffu + ((x >> 16) & 1u)) >> 16);  // RNE
}

__device__ __forceinline__ float bf2f(unsigned short u) {
    union { unsigned int i; float f; } v; v.i = ((unsigned int)u) << 16;
    return v.f;
}

__device__ __forceinline__ u16x8 pack8(float4 v0, float4 v1) {
    u16x8 o;
    o[0] = f2bf(v0.x); o[1] = f2bf(v0.y); o[2] = f2bf(v0.z); o[3] = f2bf(v0.w);
    o[4] = f2bf(v1.x); o[5] = f2bf(v1.y); o[6] = f2bf(v1.z); o[7] = f2bf(v1.w);
    return o;
}

// Inline-asm 16B global load: NOT tracked by the compiler's waitcnt logic,
// so consumption must be gated by VMWAIT below.
__device__ __forceinline__ u16x8 gload(const unsigned short* p) {
    u16x8 r;
    asm volatile("global_load_dwordx4 %0, %1, off" : "=v"(r) : "v"(p));
    return r;
}

// Counted wait: allow N loads to remain outstanding. sched_barrier(0) pins
// the following MFMAs below the wait (hipcc otherwise hoists reg-only MFMAs).
#define VMWAIT(N) do { asm volatile("s_waitcnt vmcnt(" #N ")" ::: "memory"); \
                       __builtin_amdgcn_sched_barrier(0); } while (0)

// frag-ordered LDS store: element (row, col) -> byte (col>>3)*256 + row*16 + (col&7)*2
__device__ __forceinline__ void frag_store(char* lds, int col, int row, unsigned short v) {
    *(unsigned short*)(lds + ((col >> 3) << 8) + row * 16 + ((col & 7) << 1)) = v;
}

// ---------------------------------------------------------------------------
// Setup: LDS-tiled transposes (resT, convwT) + vectorized elementwise
// ---------------------------------------------------------------------------
__global__ __launch_bounds__(256) void k_setup(
    const float* __restrict__ enc, const float* __restrict__ dec,
    const int* __restrict__ labels, const float* __restrict__ embed,
    const float* __restrict__ conv_w, const float* __restrict__ W_w,
    const float* __restrict__ Wo_w,
    unsigned short* __restrict__ s_bf, unsigned short* __restrict__ a_bf,
    unsigned short* __restrict__ dec_bf, unsigned short* __restrict__ resT,
    unsigned short* __restrict__ convwT, unsigned short* __restrict__ W_bf,
    unsigned short* __restrict__ Wo_bf) {
    __shared__ unsigned short tl[64][66];
    int bid = blockIdx.x;
    if (bid < 512) {
        const int b = bid >> 5, rem = bid & 31;
        const int s0 = (rem >> 2) << 6, e0 = (rem & 3) << 6;
#pragma unroll
        for (int it = 0; it < 16; ++it) {
            int lin = threadIdx.x + it * 256;
            int sl = lin >> 6, el = lin & 63;
            int src = (b * HWXY + s0 + sl) * EE + e0 + el;
            float dv = dec[src];
            dec_bf[src] = f2bf(dv);
            tl[sl][el] = f2bf(enc[src] + dv);
        }
        __syncthreads();
#pragma unroll
        for (int it = 0; it < 16; ++it) {
            int lin = threadIdx.x + it * 256;
            int el = lin >> 6, sl = lin & 63;
            resT[(b * EE + e0 + el) * HWXY + s0 + sl] = tl[sl][el];
        }
        return;
    }
    bid -= 512;
    if (bid < 96) {
        const int c0 = (bid >> 3) << 6, j0 = (bid & 7) << 6;
#pragma unroll
        for (int it = 0; it < 16; ++it) {
            int lin = threadIdx.x + it * 256;
            int cl = lin >> 6, jl = lin & 63;
            tl[cl][jl] = f2bf(conv_w[(c0 + cl) * 512 + j0 + jl]);
        }
        __syncthreads();
#pragma unroll
        for (int it = 0; it < 16; ++it) {
            int lin = threadIdx.x + it * 256;
            int jl = lin >> 6, cl = lin & 63;
            convwT[(j0 + jl) * 768 + c0 + cl] = tl[cl][jl];
        }
        return;
    }
    bid -= 96;
    int i8 = (bid * 256 + threadIdx.x) * 8;
    const int n1 = BB * TT * EE;
    const int n2 = EE * EE;
    if (i8 < n1) {
        int b = i8 >> 14, t = (i8 >> 8) & 63, e = i8 & 255;
        int lab = labels[b * TT + t];
        const float* ep = embed + lab * EE + e;
        float4 v0 = *(const float4*)ep, v1 = *(const float4*)(ep + 4);
        u16x8 p = pack8(v0, v1);
        *(u16x8*)(s_bf + i8) = p;
        *(u16x8*)(a_bf + i8) = p;
        return;
    }
    i8 -= n1;
    if (i8 < n2) {
        float4 v0 = *(const float4*)(W_w + i8), v1 = *(const float4*)(W_w + i8 + 4);
        *(u16x8*)(W_bf + i8) = pack8(v0, v1);
        return;
    }
    i8 -= n2;
    float4 v0 = *(const float4*)(Wo_w + i8), v1 = *(const float4*)(Wo_w + i8 + 4);
    *(u16x8*)(Wo_bf + i8) = pack8(v0, v1);
}

// ---------------------------------------------------------------------------
// Fused layer. grid 64, block 512 (8 waves). Every global B-stream is an
// explicit asm load ring with counted vmcnt (the compiler refuses to pipeline
// plain loads: r3/r4 showed VGPR=44, fully serial chains).
// ---------------------------------------------------------------------------
template <int LAST>
__global__ __launch_bounds__(512) void k_layer(
    const unsigned short* __restrict__ a_in, unsigned short* __restrict__ a_out,
    const unsigned short* __restrict__ convwT, const float* __restrict__ conv_b,
    const unsigned short* __restrict__ W_bf, const float* __restrict__ W_b,
    const unsigned short* __restrict__ s_bf, const unsigned short* __restrict__ dec_bf,
    const unsigned short* __restrict__ resT, const unsigned short* __restrict__ Wo_bf,
    const float* __restrict__ Wo_b, float* __restrict__ out) {
    __shared__ __align__(16) char a_lds[18 * 512];
    __shared__ __align__(16) char z_lds[8192];
    __shared__ __align__(16) char h_lds[8192];
    __shared__ __align__(16) char p_lds[16384];
    __shared__ float red_m[16][8];
    __shared__ float red_s[16][8];

    const int x = blockIdx.x;
    const int b = (x & 7) + (((x >> 3) >> 2) << 3);
    const int t0 = ((x >> 3) & 3) << 4;
    const int tid = threadIdx.x;
    const int w = tid >> 6, L = tid & 63;
    const int l16 = L & 15, lg = L >> 4;

    // ---- Stage conv halo tile (rows t0-1 .. t0+16) into swizzled LDS
    for (int i = tid; i < 576; i += 512) {
        const int row = i >> 5, chunk = i & 31;
        const int t = t0 - 1 + row;
        u16x8 v = {0,0,0,0,0,0,0,0};
        if (t >= 0 && t < TT) v = *(const u16x8*)(a_in + (b * TT + t) * EE + chunk * 8);
        *(u16x8*)(a_lds + row * 512 + ((chunk * 16) ^ ((row & 7) << 4))) = v;
    }
    __syncthreads();

    // ---- Phase A: conv(K=3, E->2E) + GLU. 24 k-steps x 4 streams, ring depth 4.
    f32x4 za0 = {0,0,0,0}, za1 = {0,0,0,0}, zb0 = {0,0,0,0}, zb1 = {0,0,0,0};
    {
        const unsigned short* pA0 = convwT + (w * 32 + l16) * 768 + lg * 8;
        const unsigned short* pA1 = pA0 + 16 * 768;
        const unsigned short* pB0 = pA0 + 196608;
        const unsigned short* pB1 = pA1 + 196608;
        u16x8 buf[4][4];
#pragma unroll
        for (int s = 0; s < 4; ++s) {
            buf[s][0] = gload(pA0 + s * 32);
            buf[s][1] = gload(pA1 + s * 32);
            buf[s][2] = gload(pB0 + s * 32);
            buf[s][3] = gload(pB1 + s * 32);
        }
#pragma unroll
        for (int s = 0; s < 20; ++s) {
            VMWAIT(12);
            const int arow = l16 + (s >> 3);
            const bf16x8 af = *(const bf16x8*)(
                a_lds + arow * 512 + ((((s & 7) * 64) + lg * 16) ^ ((arow & 7) << 4)));
            za0 = mfma16(af, bc(buf[s & 3][0]), za0);
            za1 = mfma16(af, bc(buf[s & 3][1]), za1);
            zb0 = mfma16(af, bc(buf[s & 3][2]), zb0);
            zb1 = mfma16(af, bc(buf[s & 3][3]), zb1);
            buf[s & 3][0] = gload(pA0 + (s + 4) * 32);
            buf[s & 3][1] = gload(pA1 + (s + 4) * 32);
            buf[s & 3][2] = gload(pB0 + (s + 4) * 32);
            buf[s & 3][3] = gload(pB1 + (s + 4) * 32);
        }
        VMWAIT(0);
#pragma unroll
        for (int s = 20; s < 24; ++s) {
            const int arow = l16 + (s >> 3);
            const bf16x8 af = *(const bf16x8*)(
                a_lds + arow * 512 + ((((s & 7) * 64) + lg * 16) ^ ((arow & 7) << 4)));
            za0 = mfma16(af, bc(buf[s & 3][0]), za0);
            za1 = mfma16(af, bc(buf[s & 3][1]), za1);
            zb0 = mfma16(af, bc(buf[s & 3][2]), zb0);
            zb1 = mfma16(af, bc(buf[s & 3][3]), zb1);
        }
    }
    float zf[2][4];
    {
        const int c0 = w * 32 + l16, c1 = c0 + 16;
        const float cbA0 = conv_b[c0], cbB0 = conv_b[c0 + 256];
        const float cbA1 = conv_b[c1], cbB1 = conv_b[c1 + 256];
#pragma unroll
        for (int j = 0; j < 4; ++j) {
            const float v0 = za0[j] + cbA0, w0 = zb0[j] + cbB0;
            const float v1 = za1[j] + cbA1, w1 = zb1[j] + cbB1;
            const float z0 = v0 / (1.0f + __expf(-w0));
            const float z1 = v1 / (1.0f + __expf(-w1));
            zf[0][j] = z0; zf[1][j] = z1;
            frag_store(z_lds, c0, lg * 4 + j, f2bf(z0));
            frag_store(z_lds, c1, lg * 4 + j, f2bf(z1));
        }
    }
    __syncthreads();

    // ---- Phase B: h = z @ W^T + W_b + s. 8 k-steps x 2 streams, ring depth 4.
    {
        f32x4 h0 = {0,0,0,0}, h1 = {0,0,0,0};
        const unsigned short* wp0 = W_bf + (w * 32 + l16) * EE + lg * 8;
        const unsigned short* wp1 = wp0 + 16 * EE;
        u16x8 buf[4][2];
#pragma unroll
        for (int s = 0; s < 4; ++s) {
            buf[s][0] = gload(wp0 + s * 32);
            buf[s][1] = gload(wp1 + s * 32);
        }
#pragma unroll
        for (int s = 0; s < 4; ++s) {
            VMWAIT(6);
            const bf16x8 af = *(const bf16x8*)(z_lds + s * 1024 + L * 16);
            h0 = mfma16(af, bc(buf[s][0]), h0);
            h1 = mfma16(af, bc(buf[s][1]), h1);
            buf[s][0] = gload(wp0 + (s + 4) * 32);
            buf[s][1] = gload(wp1 + (s + 4) * 32);
        }
        VMWAIT(0);
#pragma unroll
        for (int s = 4; s < 8; ++s) {
            const bf16x8 af = *(const bf16x8*)(z_lds + s * 1024 + L * 16);
            h0 = mfma16(af, bc(buf[s & 3][0]), h0);
            h1 = mfma16(af, bc(buf[s & 3][1]), h1);
        }
        const int c0 = w * 32 + l16, c1 = c0 + 16;
        const float wb0 = W_b[c0], wb1 = W_b[c1];
#pragma unroll
        for (int j = 0; j < 4; ++j) {
            const int row = lg * 4 + j;
            const int base = (b * TT + t0 + row) * EE;
            frag_store(h_lds, c0, row, f2bf(h0[j] + wb0 + bf2f(s_bf[base + c0])));
            frag_store(h_lds, c1, row, f2bf(h1[j] + wb1 + bf2f(s_bf[base + c1])));
        }
    }
    __syncthreads();

    // ---- Phase C: scores = h . dec^T. 8 k-steps x 4 streams, ring depth 4.
    f32x4 sc[4] = {{0,0,0,0},{0,0,0,0},{0,0,0,0},{0,0,0,0}};
    {
        const unsigned short* dp0 = dec_bf + (b * HWXY + w * 64 + l16) * EE + lg * 8;
        const unsigned short* dp1 = dp0 + 16 * EE;
        const unsigned short* dp2 = dp0 + 32 * EE;
        const unsigned short* dp3 = dp0 + 48 * EE;
        u16x8 buf[4][4];
#pragma unroll
        for (int s = 0; s < 4; ++s) {
            buf[s][0] = gload(dp0 + s * 32);
            buf[s][1] = gload(dp1 + s * 32);
            buf[s][2] = gload(dp2 + s * 32);
            buf[s][3] = gload(dp3 + s * 32);
        }
#pragma unroll
        for (int s = 0; s < 4; ++s) {
            VMWAIT(12);
            const bf16x8 af = *(const bf16x8*)(h_lds + s * 1024 + L * 16);
            sc[0] = mfma16(af, bc(buf[s][0]), sc[0]);
            sc[1] = mfma16(af, bc(buf[s][1]), sc[1]);
            sc[2] = mfma16(af, bc(buf[s][2]), sc[2]);
            sc[3] = mfma16(af, bc(buf[s][3]), sc[3]);
            buf[s][0] = gload(dp0 + (s + 4) * 32);
            buf[s][1] = gload(dp1 + (s + 4) * 32);
            buf[s][2] = gload(dp2 + (s + 4) * 32);
            buf[s][3] = gload(dp3 + (s + 4) * 32);
        }
        VMWAIT(0);
#pragma unroll
        for (int s = 4; s < 8; ++s) {
            const bf16x8 af = *(const bf16x8*)(h_lds + s * 1024 + L * 16);
            sc[0] = mfma16(af, bc(buf[s & 3][0]), sc[0]);
            sc[1] = mfma16(af, bc(buf[s & 3][1]), sc[1]);
            sc[2] = mfma16(af, bc(buf[s & 3][2]), sc[2]);
            sc[3] = mfma16(af, bc(buf[s & 3][3]), sc[3]);
        }
    }
    // softmax over s=512 across 8 waves
#pragma unroll
    for (int j = 0; j < 4; ++j) {
        float m = fmaxf(fmaxf(sc[0][j], sc[1][j]), fmaxf(sc[2][j], sc[3][j]));
#pragma unroll
        for (int off = 8; off >= 1; off >>= 1) m = fmaxf(m, __shfl_xor(m, off));
        if (l16 == 0) red_m[lg * 4 + j][w] = m;
    }
    __syncthreads();
    float sm[4];
#pragma unroll
    for (int j = 0; j < 4; ++j) {
        const int row = lg * 4 + j;
        float m = red_m[row][0];
#pragma unroll
        for (int ww = 1; ww < 8; ++ww) m = fmaxf(m, red_m[row][ww]);
        float s = 0.f;
#pragma unroll
        for (int nf = 0; nf < 4; ++nf) {
            const float p = __expf(sc[nf][j] - m);
            sc[nf][j] = p;
            s += p;
        }
#pragma unroll
        for (int off = 8; off >= 1; off >>= 1) s += __shfl_xor(s, off);
        sm[j] = s;
    }
    if (l16 == 0)
#pragma unroll
        for (int j = 0; j < 4; ++j) red_s[lg * 4 + j][w] = sm[j];
#pragma unroll
    for (int nf = 0; nf < 4; ++nf) {
        const int col = w * 64 + nf * 16 + l16;
#pragma unroll
        for (int j = 0; j < 4; ++j)
            frag_store(p_lds, col, lg * 4 + j, f2bf(sc[nf][j]));
    }
    __syncthreads();
    float inv[4];
#pragma unroll
    for (int j = 0; j < 4; ++j) {
        const int row = lg * 4 + j;
        float s = 0.f;
#pragma unroll
        for (int ww = 0; ww < 8; ++ww) s += red_s[row][ww];
        inv[j] = 1.0f / s;
    }

    // ---- Phase D: c = alpha . res^T (K=512). 16 k-steps x 2 streams, ring depth 8.
    f32x4 ca0 = {0,0,0,0}, ca1 = {0,0,0,0};
    {
        const unsigned short* rp0 = resT + (b * EE + w * 32 + l16) * HWXY + lg * 8;
        const unsigned short* rp1 = rp0 + 16 * HWXY;
        u16x8 buf[8][2];
#pragma unroll
        for (int s = 0; s < 8; ++s) {
            buf[s][0] = gload(rp0 + s * 32);
            buf[s][1] = gload(rp1 + s * 32);
        }
#pragma unroll
        for (int s = 0; s < 8; ++s) {
            VMWAIT(14);
            const bf16x8 af = *(const bf16x8*)(p_lds + s * 1024 + L * 16);
            ca0 = mfma16(af, bc(buf[s][0]), ca0);
            ca1 = mfma16(af, bc(buf[s][1]), ca1);
            buf[s][0] = gload(rp0 + (s + 8) * 32);
            buf[s][1] = gload(rp1 + (s + 8) * 32);
        }
        VMWAIT(0);
#pragma unroll
        for (int s = 8; s < 16; ++s) {
            const bf16x8 af = *(const bf16x8*)(p_lds + s * 1024 + L * 16);
            ca0 = mfma16(af, bc(buf[s & 7][0]), ca0);
            ca1 = mfma16(af, bc(buf[s & 7][1]), ca1);
        }
    }
    if (!LAST) {
        const int e0 = w * 32 + l16;
#pragma unroll
        for (int j = 0; j < 4; ++j) {
            const int row = lg * 4 + j;
            unsigned short* ap = a_out + (b * TT + t0 + row) * EE;
            ap[e0]      = f2bf(ca0[j] * inv[j] + zf[0][j]);
            ap[e0 + 16] = f2bf(ca1[j] * inv[j] + zf[1][j]);
        }
    } else {
        const int c0 = w * 32 + l16;
#pragma unroll
        for (int j = 0; j < 4; ++j) {
            const int row = lg * 4 + j;
            frag_store(z_lds, c0, row, f2bf(ca0[j] * inv[j] + zf[0][j]));
            frag_store(z_lds, c0 + 16, row, f2bf(ca1[j] * inv[j] + zf[1][j]));
        }
        __syncthreads();
        // ---- Phase E: logits + log_softmax. 8 k-steps x 1 stream, ring depth 4.
        f32x4 la = {0,0,0,0};
        const int v = w * 16 + l16;
        {
            const unsigned short* wo = Wo_bf + v * EE + lg * 8;
            u16x8 buf[4];
#pragma unroll
            for (int s = 0; s < 4; ++s) buf[s] = gload(wo + s * 32);
#pragma unroll
            for (int s = 0; s < 4; ++s) {
                VMWAIT(3);
                const bf16x8 af = *(const bf16x8*)(z_lds + s * 1024 + L * 16);
                la = mfma16(af, bc(buf[s]), la);
                buf[s] = gload(wo + (s + 4) * 32);
            }
            VMWAIT(0);
#pragma unroll
            for (int s = 4; s < 8; ++s) {
                const bf16x8 af = *(const bf16x8*)(z_lds + s * 1024 + L * 16);
                la = mfma16(af, bc(buf[s & 3]), la);
            }
        }
        const float wb = Wo_b[v];
        float lv[4], mg[4];
#pragma unroll
        for (int j = 0; j < 4; ++j) {
            lv[j] = la[j] + wb;
            float m = lv[j];
#pragma unroll
            for (int off = 8; off >= 1; off >>= 1) m = fmaxf(m, __shfl_xor(m, off));
            if (l16 == 0) red_m[lg * 4 + j][w] = m;
        }
        __syncthreads();
#pragma unroll
        for (int j = 0; j < 4; ++j) {
            const int row = lg * 4 + j;
            float m = red_m[row][0];
#pragma unroll
            for (int ww = 1; ww < 8; ++ww) m = fmaxf(m, red_m[row][ww]);
            mg[j] = m;
            float s = __expf(lv[j] - m);
#pragma unroll
            for (int off = 8; off >= 1; off >>= 1) s += __shfl_xor(s, off);
            if (l16 == 0) red_s[row][w] = s;
        }
        __syncthreads();
#pragma unroll
        for (int j = 0; j < 4; ++j) {
            const int row = lg * 4 + j;
            float s = 0.f;
#pragma unroll
            for (int ww = 0; ww < 8; ++ww) s += red_s[row][ww];
            const float lse = mg[j] + __logf(s);
            out[(b * TT + t0 + row) * VV + v] = lv[j] - lse;
        }
    }
}

// ---------------------------------------------------------------------------
extern "C" void kernel_launch(void* const* d_in, const int* in_sizes, int n_in,
                              void* d_out, int out_size, void* d_ws, size_t ws_size,
                              hipStream_t stream) {
    const float* enc    = (const float*)d_in[0];
    const float* dec    = (const float*)d_in[1];
    const int*   labels = (const int*)d_in[2];
    const float* embed  = (const float*)d_in[3];
    const float* conv_w = (const float*)d_in[4];
    const float* conv_b = (const float*)d_in[5];
    const float* W_w    = (const float*)d_in[6];
    const float* W_b    = (const float*)d_in[7];
    const float* Wo_w   = (const float*)d_in[8];
    const float* Wo_b   = (const float*)d_in[9];
    float* out = (float*)d_out;
    char* ws = (char*)d_ws;

    unsigned short* a0     = (unsigned short*)(ws + 0x000000);
    unsigned short* a1     = (unsigned short*)(ws + 0x080000);
    unsigned short* s_bf   = (unsigned short*)(ws + 0x100000);
    unsigned short* dec_bf = (unsigned short*)(ws + 0x180000);
    unsigned short* resT   = (unsigned short*)(ws + 0x580000);
    unsigned short* convwT = (unsigned short*)(ws + 0x980000);
    unsigned short* W_bf   = (unsigned short*)(ws + 0xA40000);
    unsigned short* Wo_bf  = (unsigned short*)(ws + 0xA60000);

    k_setup<<<784, 256, 0, stream>>>(enc, dec, labels, embed, conv_w, W_w, Wo_w,
                                     s_bf, a0, dec_bf, resT, convwT, W_bf, Wo_bf);

    k_layer<0><<<64, 512, 0, stream>>>(a0, a1, convwT, conv_b, W_bf, W_b, s_bf,
                                       dec_bf, resT, Wo_bf, Wo_b, out);
    k_layer<0><<<64, 512, 0, stream>>>(a1, a0, convwT, conv_b, W_bf, W_b, s_bf,
                                       dec_bf, resT, Wo_bf, Wo_b, out);
    k_layer<1><<<64, 512, 0, stream>>>(a0, a1, convwT, conv_b, W_bf, W_b, s_bf,
                                       dec_bf, resT, Wo_bf, Wo_b, out);
}

// Round 6
// 147.742 us; speedup vs baseline: 1.0095x; 1.0095x over previous
//
#include <hip/hip_runtime.h>
#include <hip/hip_bf16.h>
#include <math.h>

#define BB 16
#define TT 64
#define HWXY 512
#define EE 256
#define VV 128

typedef __bf16 bf16x8 __attribute__((ext_vector_type(8)));
typedef unsigned short u16x8 __attribute__((ext_vector_type(8)));
typedef float f32x4 __attribute__((ext_vector_type(4)));

__device__ __forceinline__ f32x4 mfma16(bf16x8 a, bf16x8 b, f32x4 c) {
    return __builtin_amdgcn_mfma_f32_16x16x32_bf16(a, b, c, 0, 0, 0);
}

__device__ __forceinline__ unsigned short f2bf(float f) {
    union { float f; unsigned int i; } v; v.f = f;
    unsigned int x = v.i;
    return (unsigned short)((x + 0x7fffu + ((x >> 16) & 1u)) >> 16);  // RNE
}

__device__ __forceinline__ float bf2f(unsigned short u) {
    union { unsigned int i; float f; } v; v.i = ((unsigned int)u) << 16;
    return v.f;
}

__device__ __forceinline__ u16x8 pack8(float4 v0, float4 v1) {
    u16x8 o;
    o[0] = f2bf(v0.x); o[1] = f2bf(v0.y); o[2] = f2bf(v0.z); o[3] = f2bf(v0.w);
    o[4] = f2bf(v1.x); o[5] = f2bf(v1.y); o[6] = f2bf(v1.z); o[7] = f2bf(v1.w);
    return o;
}

// Async global->LDS DMA, 16B per lane. Global src is PER-LANE; LDS dest is
// wave-uniform base, HW scatters lane i to base + i*16. No dest VGPR => the
// register allocator cannot collapse the pipeline (r4/r5 failure mode).
__device__ __forceinline__ void dma16(const void* g, void* l) {
    __builtin_amdgcn_global_load_lds(
        (const __attribute__((address_space(1))) void*)g,
        (__attribute__((address_space(3))) void*)l, 16, 0, 0);
}

// Counted wait on the DMA queue + scheduler fence (rule #18).
#define VMWAIT(N) do { asm volatile("s_waitcnt vmcnt(" #N ")" ::: "memory"); \
                       __builtin_amdgcn_sched_barrier(0); } while (0)
#define SCHED0() __builtin_amdgcn_sched_barrier(0)

// frag-ordered LDS store: element (row, col) -> byte (col>>3)*256 + row*16 + (col&7)*2
__device__ __forceinline__ void frag_store(char* lds, int col, int row, unsigned short v) {
    *(unsigned short*)(lds + ((col >> 3) << 8) + row * 16 + ((col & 7) << 1)) = v;
}

// ---------------------------------------------------------------------------
// Setup: LDS-tiled transposes (resT, convwT) + vectorized elementwise
// ---------------------------------------------------------------------------
__global__ __launch_bounds__(256) void k_setup(
    const float* __restrict__ enc, const float* __restrict__ dec,
    const int* __restrict__ labels, const float* __restrict__ embed,
    const float* __restrict__ conv_w, const float* __restrict__ W_w,
    const float* __restrict__ Wo_w,
    unsigned short* __restrict__ s_bf, unsigned short* __restrict__ a_bf,
    unsigned short* __restrict__ dec_bf, unsigned short* __restrict__ resT,
    unsigned short* __restrict__ convwT, unsigned short* __restrict__ W_bf,
    unsigned short* __restrict__ Wo_bf) {
    __shared__ unsigned short tl[64][66];
    int bid = blockIdx.x;
    if (bid < 512) {
        const int b = bid >> 5, rem = bid & 31;
        const int s0 = (rem >> 2) << 6, e0 = (rem & 3) << 6;
#pragma unroll
        for (int it = 0; it < 16; ++it) {
            int lin = threadIdx.x + it * 256;
            int sl = lin >> 6, el = lin & 63;
            int src = (b * HWXY + s0 + sl) * EE + e0 + el;
            float dv = dec[src];
            dec_bf[src] = f2bf(dv);
            tl[sl][el] = f2bf(enc[src] + dv);
        }
        __syncthreads();
#pragma unroll
        for (int it = 0; it < 16; ++it) {
            int lin = threadIdx.x + it * 256;
            int el = lin >> 6, sl = lin & 63;
            resT[(b * EE + e0 + el) * HWXY + s0 + sl] = tl[sl][el];
        }
        return;
    }
    bid -= 512;
    if (bid < 96) {
        const int c0 = (bid >> 3) << 6, j0 = (bid & 7) << 6;
#pragma unroll
        for (int it = 0; it < 16; ++it) {
            int lin = threadIdx.x + it * 256;
            int cl = lin >> 6, jl = lin & 63;
            tl[cl][jl] = f2bf(conv_w[(c0 + cl) * 512 + j0 + jl]);
        }
        __syncthreads();
#pragma unroll
        for (int it = 0; it < 16; ++it) {
            int lin = threadIdx.x + it * 256;
            int jl = lin >> 6, cl = lin & 63;
            convwT[(j0 + jl) * 768 + c0 + cl] = tl[cl][jl];
        }
        return;
    }
    bid -= 96;
    int i8 = (bid * 256 + threadIdx.x) * 8;
    const int n1 = BB * TT * EE;
    const int n2 = EE * EE;
    if (i8 < n1) {
        int b = i8 >> 14, t = (i8 >> 8) & 63, e = i8 & 255;
        int lab = labels[b * TT + t];
        const float* ep = embed + lab * EE + e;
        float4 v0 = *(const float4*)ep, v1 = *(const float4*)(ep + 4);
        u16x8 p = pack8(v0, v1);
        *(u16x8*)(s_bf + i8) = p;
        *(u16x8*)(a_bf + i8) = p;
        return;
    }
    i8 -= n1;
    if (i8 < n2) {
        float4 v0 = *(const float4*)(W_w + i8), v1 = *(const float4*)(W_w + i8 + 4);
        *(u16x8*)(W_bf + i8) = pack8(v0, v1);
        return;
    }
    i8 -= n2;
    float4 v0 = *(const float4*)(Wo_w + i8), v1 = *(const float4*)(Wo_w + i8 + 4);
    *(u16x8*)(Wo_bf + i8) = pack8(v0, v1);
}

// ---------------------------------------------------------------------------
// Fused layer. grid 64, block 512 (8 waves). All B-operands staged via
// global_load_lds into a per-wave 16KB LDS ring (4 slots x 4KB), consumed
// with counted vmcnt in ROLLED loops (small code, deep DMA queue).
// LDS map (154KB):
//   [0,9216)        a halo tile (phase A)        } aliased by p_lds
//   [9216,17408)    z frags (phase B)            } (dead after B barrier)
//   [17408,25600)   h frags (phase C)  / a frags (phase E, LAST)
//   [25600,26624)   red_m/red_s
//   [26624,157696)  stage ring, 8 waves x 16KB
// ---------------------------------------------------------------------------
template <int LAST>
__global__ __launch_bounds__(512) void k_layer(
    const unsigned short* __restrict__ a_in, unsigned short* __restrict__ a_out,
    const unsigned short* __restrict__ convwT, const float* __restrict__ conv_b,
    const unsigned short* __restrict__ W_bf, const float* __restrict__ W_b,
    const unsigned short* __restrict__ s_bf, const unsigned short* __restrict__ dec_bf,
    const unsigned short* __restrict__ resT, const unsigned short* __restrict__ Wo_bf,
    const float* __restrict__ Wo_b, float* __restrict__ out) {
    __shared__ __align__(16) char smem[157696];
    char* const A_LDSp = smem;
    char* const Z_LDSp = smem + 9216;
    char* const H_LDSp = smem + 17408;
    char* const P_LDSp = smem;            // aliases A+Z (dead after B barrier)
    char* const E_LDSp = smem + 17408;    // aliases H (LAST only, after barrier)
    float* const red_m = (float*)(smem + 25600);   // [16][8]
    float* const red_s = (float*)(smem + 26112);   // [16][8]
    char* const stage = smem + 26624;

    const int x = blockIdx.x;
    const int b = (x & 7) + ((x >> 5) << 3);        // XCD swizzle
    const int t0 = ((x >> 3) & 3) << 4;
    const int tid = threadIdx.x;
    const int w = tid >> 6, L = tid & 63;
    const int l16 = L & 15, lg = L >> 4;
    char* const ring = stage + w * 16384;           // 4 slots x 4096

    // ---- Prefetch all epilogue scalars (tiny, hides under phase A)
    const int c0 = w * 32 + l16, c1 = c0 + 16;
    const float cbA0 = conv_b[c0], cbB0 = conv_b[c0 + 256];
    const float cbA1 = conv_b[c1], cbB1 = conv_b[c1 + 256];
    const float wb0 = W_b[c0], wb1 = W_b[c1];
    unsigned short sv0[4], sv1[4];
#pragma unroll
    for (int j = 0; j < 4; ++j) {
        const int base = (b * TT + t0 + lg * 4 + j) * EE;
        sv0[j] = s_bf[base + c0];
        sv1[j] = s_bf[base + c1];
    }
    float wob = 0.f;
    if (LAST) wob = Wo_b[w * 16 + l16];

    // ---- Stage conv halo tile (rows t0-1 .. t0+16), XOR-swizzled
    for (int i = tid; i < 576; i += 512) {
        const int row = i >> 5, chunk = i & 31;
        const int t = t0 - 1 + row;
        u16x8 v = {0,0,0,0,0,0,0,0};
        if (t >= 0 && t < TT) v = *(const u16x8*)(a_in + (b * TT + t) * EE + chunk * 8);
        *(u16x8*)(A_LDSp + row * 512 + ((chunk * 16) ^ ((row & 7) << 4))) = v;
    }

    // ---- Phase A DMA prologue (drained by the barrier below)
    const unsigned short* gA0 = convwT + c0 * 768 + lg * 8;
    const unsigned short* gA1 = gA0 + 16 * 768;
    const unsigned short* gB0 = gA0 + 196608;
    const unsigned short* gB1 = gA1 + 196608;
#pragma unroll
    for (int s = 0; s < 4; ++s) {
        char* sl = ring + s * 4096;
        dma16(gA0 + s * 32, sl);
        dma16(gA1 + s * 32, sl + 1024);
        dma16(gB0 + s * 32, sl + 2048);
        dma16(gB1 + s * 32, sl + 3072);
    }
    __syncthreads();

    // ---- Phase A: conv(K=3, E->2E) + GLU. 24 k-steps, ring depth 4.
    f32x4 za0 = {0,0,0,0}, za1 = {0,0,0,0}, zb0 = {0,0,0,0}, zb1 = {0,0,0,0};
    auto stepA = [&](int s) {
        char* sl = ring + (s & 3) * 4096;
        const int arow = l16 + (s >> 3);
        const bf16x8 af = *(const bf16x8*)(
            A_LDSp + arow * 512 + ((((s & 7) << 6) + lg * 16) ^ ((arow & 7) << 4)));
        const bf16x8 b0 = *(const bf16x8*)(sl + L * 16);
        const bf16x8 b1 = *(const bf16x8*)(sl + 1024 + L * 16);
        const bf16x8 b2 = *(const bf16x8*)(sl + 2048 + L * 16);
        const bf16x8 b3 = *(const bf16x8*)(sl + 3072 + L * 16);
        za0 = mfma16(af, b0, za0);
        za1 = mfma16(af, b1, za1);
        zb0 = mfma16(af, b2, zb0);
        zb1 = mfma16(af, b3, zb1);
    };
#pragma unroll 1
    for (int s = 0; s < 20; ++s) {
        VMWAIT(12);
        stepA(s);
        SCHED0();
        char* sl = ring + (s & 3) * 4096;
        dma16(gA0 + (s + 4) * 32, sl);
        dma16(gA1 + (s + 4) * 32, sl + 1024);
        dma16(gB0 + (s + 4) * 32, sl + 2048);
        dma16(gB1 + (s + 4) * 32, sl + 3072);
    }
    VMWAIT(0);
#pragma unroll 1
    for (int s = 20; s < 24; ++s) stepA(s);
    SCHED0();

    // ---- Phase B DMA prologue: whole W tile (16KB), drained by barrier
    const unsigned short* wp0 = W_bf + c0 * EE + lg * 8;
    const unsigned short* wp1 = wp0 + 16 * EE;
#pragma unroll 1
    for (int kc = 0; kc < 8; ++kc) {
        dma16(wp0 + kc * 32, ring + kc * 2048);
        dma16(wp1 + kc * 32, ring + kc * 2048 + 1024);
    }

    // z epilogue: GLU, save zf, write z frags
    float zf0[4], zf1[4];
#pragma unroll
    for (int j = 0; j < 4; ++j) {
        const float v0 = za0[j] + cbA0, w0 = zb0[j] + cbB0;
        const float v1 = za1[j] + cbA1, w1 = zb1[j] + cbB1;
        const float z0 = v0 / (1.0f + __expf(-w0));
        const float z1 = v1 / (1.0f + __expf(-w1));
        zf0[j] = z0; zf1[j] = z1;
        frag_store(Z_LDSp, c0, lg * 4 + j, f2bf(z0));
        frag_store(Z_LDSp, c1, lg * 4 + j, f2bf(z1));
    }
    __syncthreads();

    // ---- Phase B: h = z @ W^T + W_b + s. 8 k-steps, fully staged.
    f32x4 h0 = {0,0,0,0}, h1 = {0,0,0,0};
    VMWAIT(0);
#pragma unroll 1
    for (int kc = 0; kc < 8; ++kc) {
        const bf16x8 af = *(const bf16x8*)(Z_LDSp + kc * 1024 + L * 16);
        const bf16x8 w0 = *(const bf16x8*)(ring + kc * 2048 + L * 16);
        const bf16x8 w1 = *(const bf16x8*)(ring + kc * 2048 + 1024 + L * 16);
        h0 = mfma16(af, w0, h0);
        h1 = mfma16(af, w1, h1);
    }
    SCHED0();

    // ---- Phase C DMA prologue (slots 0..3), drained by barrier below
    const unsigned short* dp0 = dec_bf + (b * HWXY + w * 64 + l16) * EE + lg * 8;
    const unsigned short* dp1 = dp0 + 16 * EE;
    const unsigned short* dp2 = dp0 + 32 * EE;
    const unsigned short* dp3 = dp0 + 48 * EE;
#pragma unroll 1
    for (int s = 0; s < 4; ++s) {
        char* sl = ring + s * 4096;
        dma16(dp0 + s * 32, sl);
        dma16(dp1 + s * 32, sl + 1024);
        dma16(dp2 + s * 32, sl + 2048);
        dma16(dp3 + s * 32, sl + 3072);
    }

    // h epilogue (register-only: sv/wb prefetched)
#pragma unroll
    for (int j = 0; j < 4; ++j) {
        const int row = lg * 4 + j;
        frag_store(H_LDSp, c0, row, f2bf(h0[j] + wb0 + bf2f(sv0[j])));
        frag_store(H_LDSp, c1, row, f2bf(h1[j] + wb1 + bf2f(sv1[j])));
    }
    __syncthreads();

    // ---- Phase C: scores = h . dec^T. 8 k-steps, ring depth 4.
    f32x4 sc[4] = {{0,0,0,0},{0,0,0,0},{0,0,0,0},{0,0,0,0}};
    auto stepC = [&](int s) {
        char* sl = ring + (s & 3) * 4096;
        const bf16x8 af = *(const bf16x8*)(H_LDSp + s * 1024 + L * 16);
        sc[0] = mfma16(af, *(const bf16x8*)(sl + L * 16), sc[0]);
        sc[1] = mfma16(af, *(const bf16x8*)(sl + 1024 + L * 16), sc[1]);
        sc[2] = mfma16(af, *(const bf16x8*)(sl + 2048 + L * 16), sc[2]);
        sc[3] = mfma16(af, *(const bf16x8*)(sl + 3072 + L * 16), sc[3]);
    };
#pragma unroll 1
    for (int s = 0; s < 4; ++s) {
        VMWAIT(12);
        stepC(s);
        SCHED0();
        char* sl = ring + (s & 3) * 4096;
        dma16(dp0 + (s + 4) * 32, sl);
        dma16(dp1 + (s + 4) * 32, sl + 1024);
        dma16(dp2 + (s + 4) * 32, sl + 2048);
        dma16(dp3 + (s + 4) * 32, sl + 3072);
    }
    VMWAIT(0);
#pragma unroll 1
    for (int s = 4; s < 8; ++s) stepC(s);
    SCHED0();

    // ---- Phase D DMA prologue (super-steps 0..3), hides under softmax
    const unsigned short* rp0 = resT + (b * EE + c0) * HWXY + lg * 8;
    const unsigned short* rp1 = rp0 + 16 * HWXY;
#pragma unroll 1
    for (int S = 0; S < 4; ++S) {
        char* sl = ring + S * 4096;
        dma16(rp0 + (2 * S) * 32, sl);
        dma16(rp1 + (2 * S) * 32, sl + 1024);
        dma16(rp0 + (2 * S + 1) * 32, sl + 2048);
        dma16(rp1 + (2 * S + 1) * 32, sl + 3072);
    }

    // ---- Softmax over s=512 across 8 waves
#pragma unroll
    for (int j = 0; j < 4; ++j) {
        float m = fmaxf(fmaxf(sc[0][j], sc[1][j]), fmaxf(sc[2][j], sc[3][j]));
#pragma unroll
        for (int off = 8; off >= 1; off >>= 1) m = fmaxf(m, __shfl_xor(m, off));
        if (l16 == 0) red_m[(lg * 4 + j) * 8 + w] = m;
    }
    __syncthreads();
    float sm[4];
#pragma unroll
    for (int j = 0; j < 4; ++j) {
        const int row = lg * 4 + j;
        float m = red_m[row * 8 + 0];
#pragma unroll
        for (int ww = 1; ww < 8; ++ww) m = fmaxf(m, red_m[row * 8 + ww]);
        float s = 0.f;
#pragma unroll
        for (int nf = 0; nf < 4; ++nf) {
            const float p = __expf(sc[nf][j] - m);
            sc[nf][j] = p;
            s += p;
        }
#pragma unroll
        for (int off = 8; off >= 1; off >>= 1) s += __shfl_xor(s, off);
        sm[j] = s;
    }
    if (l16 == 0)
#pragma unroll
        for (int j = 0; j < 4; ++j) red_s[(lg * 4 + j) * 8 + w] = sm[j];
    // unnormalized p -> frag LDS (aliases a/z regions: both dead now)
#pragma unroll
    for (int nf = 0; nf < 4; ++nf) {
        const int col = w * 64 + nf * 16 + l16;
#pragma unroll
        for (int j = 0; j < 4; ++j)
            frag_store(P_LDSp, col, lg * 4 + j, f2bf(sc[nf][j]));
    }
    __syncthreads();
    float inv[4];
#pragma unroll
    for (int j = 0; j < 4; ++j) {
        const int row = lg * 4 + j;
        float s = 0.f;
#pragma unroll
        for (int ww = 0; ww < 8; ++ww) s += red_s[row * 8 + ww];
        inv[j] = 1.0f / s;
    }

    // ---- Phase D: c = alpha . res^T (K=512). 8 super-steps, ring depth 4.
    f32x4 ca0 = {0,0,0,0}, ca1 = {0,0,0,0};
    auto stepD = [&](int S) {
        char* sl = ring + (S & 3) * 4096;
        const bf16x8 a0 = *(const bf16x8*)(P_LDSp + (2 * S) * 1024 + L * 16);
        const bf16x8 a1 = *(const bf16x8*)(P_LDSp + (2 * S + 1) * 1024 + L * 16);
        ca0 = mfma16(a0, *(const bf16x8*)(sl + L * 16), ca0);
        ca1 = mfma16(a0, *(const bf16x8*)(sl + 1024 + L * 16), ca1);
        ca0 = mfma16(a1, *(const bf16x8*)(sl + 2048 + L * 16), ca0);
        ca1 = mfma16(a1, *(const bf16x8*)(sl + 3072 + L * 16), ca1);
    };
#pragma unroll 1
    for (int S = 0; S < 4; ++S) {
        VMWAIT(12);
        stepD(S);
        SCHED0();
        char* sl = ring + (S & 3) * 4096;
        dma16(rp0 + (2 * S + 8) * 32, sl);
        dma16(rp1 + (2 * S + 8) * 32, sl + 1024);
        dma16(rp0 + (2 * S + 9) * 32, sl + 2048);
        dma16(rp1 + (2 * S + 9) * 32, sl + 3072);
    }
    VMWAIT(0);
#pragma unroll 1
    for (int S = 4; S < 8; ++S) stepD(S);
    SCHED0();

    if (!LAST) {
#pragma unroll
        for (int j = 0; j < 4; ++j) {
            const int row = lg * 4 + j;
            unsigned short* ap = a_out + (b * TT + t0 + row) * EE;
            ap[c0] = f2bf(ca0[j] * inv[j] + zf0[j]);
            ap[c1] = f2bf(ca1[j] * inv[j] + zf1[j]);
        }
    } else {
        // ---- Phase E DMA prologue: Wo rows (8KB), hides under barrier
        const unsigned short* wo = Wo_bf + (w * 16 + l16) * EE + lg * 8;
#pragma unroll 1
        for (int kc = 0; kc < 8; ++kc) dma16(wo + kc * 32, ring + kc * 1024);
        // a -> frag LDS (aliases h region; h dead after C)
#pragma unroll
        for (int j = 0; j < 4; ++j) {
            const int row = lg * 4 + j;
            frag_store(E_LDSp, c0, row, f2bf(ca0[j] * inv[j] + zf0[j]));
            frag_store(E_LDSp, c1, row, f2bf(ca1[j] * inv[j] + zf1[j]));
        }
        __syncthreads();
        // ---- Phase E: logits = a @ Wo^T + Wo_b; log_softmax over V=128
        f32x4 la = {0,0,0,0};
        VMWAIT(0);
#pragma unroll 1
        for (int kc = 0; kc < 8; ++kc) {
            const bf16x8 af = *(const bf16x8*)(E_LDSp + kc * 1024 + L * 16);
            la = mfma16(af, *(const bf16x8*)(ring + kc * 1024 + L * 16), la);
        }
        float lv[4], mg[4];
#pragma unroll
        for (int j = 0; j < 4; ++j) {
            lv[j] = la[j] + wob;
            float m = lv[j];
#pragma unroll
            for (int off = 8; off >= 1; off >>= 1) m = fmaxf(m, __shfl_xor(m, off));
            if (l16 == 0) red_m[(lg * 4 + j) * 8 + w] = m;
        }
        __syncthreads();
#pragma unroll
        for (int j = 0; j < 4; ++j) {
            const int row = lg * 4 + j;
            float m = red_m[row * 8 + 0];
#pragma unroll
            for (int ww = 1; ww < 8; ++ww) m = fmaxf(m, red_m[row * 8 + ww]);
            mg[j] = m;
            float s = __expf(lv[j] - m);
#pragma unroll
            for (int off = 8; off >= 1; off >>= 1) s += __shfl_xor(s, off);
            if (l16 == 0) red_s[row * 8 + w] = s;
        }
        __syncthreads();
#pragma unroll
        for (int j = 0; j < 4; ++j) {
            const int row = lg * 4 + j;
            float s = 0.f;
#pragma unroll
            for (int ww = 0; ww < 8; ++ww) s += red_s[row * 8 + ww];
            const float lse = mg[j] + __logf(s);
            out[(b * TT + t0 + row) * VV + w * 16 + l16] = lv[j] - lse;
        }
    }
}

// ---------------------------------------------------------------------------
extern "C" void kernel_launch(void* const* d_in, const int* in_sizes, int n_in,
                              void* d_out, int out_size, void* d_ws, size_t ws_size,
                              hipStream_t stream) {
    const float* enc    = (const float*)d_in[0];
    const float* dec    = (const float*)d_in[1];
    const int*   labels = (const int*)d_in[2];
    const float* embed  = (const float*)d_in[3];
    const float* conv_w = (const float*)d_in[4];
    const float* conv_b = (const float*)d_in[5];
    const float* W_w    = (const float*)d_in[6];
    const float* W_b    = (const float*)d_in[7];
    const float* Wo_w   = (const float*)d_in[8];
    const float* Wo_b   = (const float*)d_in[9];
    float* out = (float*)d_out;
    char* ws = (char*)d_ws;

    unsigned short* a0     = (unsigned short*)(ws + 0x000000);
    unsigned short* a1     = (unsigned short*)(ws + 0x080000);
    unsigned short* s_bf   = (unsigned short*)(ws + 0x100000);
    unsigned short* dec_bf = (unsigned short*)(ws + 0x180000);
    unsigned short* resT   = (unsigned short*)(ws + 0x580000);
    unsigned short* convwT = (unsigned short*)(ws + 0x980000);
    unsigned short* W_bf   = (unsigned short*)(ws + 0xA40000);
    unsigned short* Wo_bf  = (unsigned short*)(ws + 0xA60000);

    k_setup<<<784, 256, 0, stream>>>(enc, dec, labels, embed, conv_w, W_w, Wo_w,
                                     s_bf, a0, dec_bf, resT, convwT, W_bf, Wo_bf);

    k_layer<0><<<64, 512, 0, stream>>>(a0, a1, convwT, conv_b, W_bf, W_b, s_bf,
                                       dec_bf, resT, Wo_bf, Wo_b, out);
    k_layer<0><<<64, 512, 0, stream>>>(a1, a0, convwT, conv_b, W_bf, W_b, s_bf,
                                       dec_bf, resT, Wo_bf, Wo_b, out);
    k_layer<1><<<64, 512, 0, stream>>>(a0, a1, convwT, conv_b, W_bf, W_b, s_bf,
                                       dec_bf, resT, Wo_bf, Wo_b, out);
}

// Round 7
// 86.909 us; speedup vs baseline: 1.7161x; 1.7000x over previous
//
#include <hip/hip_runtime.h>
#include <hip/hip_bf16.h>
#include <math.h>

#define BB 16
#define TT 64
#define HWXY 512
#define EE 256
#define VV 128

typedef __bf16 bf16x8 __attribute__((ext_vector_type(8)));
typedef unsigned short u16x8 __attribute__((ext_vector_type(8)));
typedef float f32x4 __attribute__((ext_vector_type(4)));

__device__ __forceinline__ f32x4 mfma16(bf16x8 a, bf16x8 b, f32x4 c) {
    return __builtin_amdgcn_mfma_f32_16x16x32_bf16(a, b, c, 0, 0, 0);
}

__device__ __forceinline__ unsigned short f2bf(float f) {
    union { float f; unsigned int i; } v; v.f = f;
    unsigned int x = v.i;
    return (unsigned short)((x + 0x7fffu + ((x >> 16) & 1u)) >> 16);  // RNE
}

__device__ __forceinline__ float bf2f(unsigned short u) {
    union { unsigned int i; float f; } v; v.i = ((unsigned int)u) << 16;
    return v.f;
}

__device__ __forceinline__ u16x8 pack8(float4 v0, float4 v1) {
    u16x8 o;
    o[0] = f2bf(v0.x); o[1] = f2bf(v0.y); o[2] = f2bf(v0.z); o[3] = f2bf(v0.w);
    o[4] = f2bf(v1.x); o[5] = f2bf(v1.y); o[6] = f2bf(v1.z); o[7] = f2bf(v1.w);
    return o;
}

// ---------------------------------------------------------------------------
// Setup: LDS-tiled transposes (resT, convwT) + vectorized elementwise
// ---------------------------------------------------------------------------
__global__ __launch_bounds__(256) void k_setup(
    const float* __restrict__ enc, const float* __restrict__ dec,
    const int* __restrict__ labels, const float* __restrict__ embed,
    const float* __restrict__ conv_w, const float* __restrict__ W_w,
    const float* __restrict__ Wo_w,
    unsigned short* __restrict__ s_bf, unsigned short* __restrict__ a_bf,
    unsigned short* __restrict__ dec_bf, unsigned short* __restrict__ resT,
    unsigned short* __restrict__ convwT, unsigned short* __restrict__ W_bf,
    unsigned short* __restrict__ Wo_bf) {
    __shared__ unsigned short tl[64][66];
    int bid = blockIdx.x;
    if (bid < 512) {
        const int b = bid >> 5, rem = bid & 31;
        const int s0 = (rem >> 2) << 6, e0 = (rem & 3) << 6;
#pragma unroll
        for (int it = 0; it < 16; ++it) {
            int lin = threadIdx.x + it * 256;
            int sl = lin >> 6, el = lin & 63;
            int src = (b * HWXY + s0 + sl) * EE + e0 + el;
            float dv = dec[src];
            dec_bf[src] = f2bf(dv);
            tl[sl][el] = f2bf(enc[src] + dv);
        }
        __syncthreads();
#pragma unroll
        for (int it = 0; it < 16; ++it) {
            int lin = threadIdx.x + it * 256;
            int el = lin >> 6, sl = lin & 63;
            resT[(b * EE + e0 + el) * HWXY + s0 + sl] = tl[sl][el];
        }
        return;
    }
    bid -= 512;
    if (bid < 96) {
        const int c0 = (bid >> 3) << 6, j0 = (bid & 7) << 6;
#pragma unroll
        for (int it = 0; it < 16; ++it) {
            int lin = threadIdx.x + it * 256;
            int cl = lin >> 6, jl = lin & 63;
            tl[cl][jl] = f2bf(conv_w[(c0 + cl) * 512 + j0 + jl]);
        }
        __syncthreads();
#pragma unroll
        for (int it = 0; it < 16; ++it) {
            int lin = threadIdx.x + it * 256;
            int jl = lin >> 6, cl = lin & 63;
            convwT[(j0 + jl) * 768 + c0 + cl] = tl[cl][jl];
        }
        return;
    }
    bid -= 96;
    int i8 = (bid * 256 + threadIdx.x) * 8;
    const int n1 = BB * TT * EE;
    const int n2 = EE * EE;
    if (i8 < n1) {
        int b = i8 >> 14, t = (i8 >> 8) & 63, e = i8 & 255;
        int lab = labels[b * TT + t];
        const float* ep = embed + lab * EE + e;
        float4 v0 = *(const float4*)ep, v1 = *(const float4*)(ep + 4);
        u16x8 p = pack8(v0, v1);
        *(u16x8*)(s_bf + i8) = p;
        *(u16x8*)(a_bf + i8) = p;
        return;
    }
    i8 -= n1;
    if (i8 < n2) {
        float4 v0 = *(const float4*)(W_w + i8), v1 = *(const float4*)(W_w + i8 + 4);
        *(u16x8*)(W_bf + i8) = pack8(v0, v1);
        return;
    }
    i8 -= n2;
    float4 v0 = *(const float4*)(Wo_w + i8), v1 = *(const float4*)(Wo_w + i8 + 4);
    *(u16x8*)(Wo_bf + i8) = pack8(v0, v1);
}

// ---------------------------------------------------------------------------
// K1: conv(K=3,E->2E)+GLU -> z.  grid (ct=16, b=16), block 256 (4 waves).
// Block: 64 t-rows x 16 pairs. A halo (33KB) + B slice (48KB) staged in LDS.
// ---------------------------------------------------------------------------
__global__ __launch_bounds__(256) void k_conv(
    const unsigned short* __restrict__ a_in, const unsigned short* __restrict__ convwT,
    const float* __restrict__ conv_b, unsigned short* __restrict__ z_bf) {
    __shared__ __align__(16) char As[33792];   // 66 rows x 512B, swizzled
    __shared__ __align__(16) char Bs[49152];   // frag-order, 32 j x 768 k
    const int ct = blockIdx.x, b = blockIdx.y;
    const int tid = threadIdx.x;
    const int w = tid >> 6, L = tid & 63, l16 = L & 15, lg = L >> 4;

#pragma unroll
    for (int it = 0; it < 9; ++it) {
        int unit = tid + it * 256;
        if (unit < 2112) {
            int row = unit >> 5, ch = unit & 31;
            int t = row - 1;
            u16x8 v = {0,0,0,0,0,0,0,0};
            if (t >= 0 && t < TT) v = *(const u16x8*)(a_in + (b * TT + t) * EE + ch * 8);
            *(u16x8*)(As + row * 512 + ((ch * 16) ^ ((row & 7) << 4))) = v;
        }
    }
    {
        const int row = tid >> 3;
        const int jg = ct * 16 + (row & 15) + ((row >> 4) << 8);
        const unsigned short* src = convwT + jg * 768;
#pragma unroll
        for (int it = 0; it < 12; ++it) {
            int ch = (tid & 7) + it * 8;
            u16x8 v = *(const u16x8*)(src + ch * 8);
            *(u16x8*)(Bs + ((ch >> 2) * 2 + (row >> 4)) * 1024 + (ch & 3) * 256 + (row & 15) * 16) = v;
        }
    }
    __syncthreads();

    f32x4 za = {0,0,0,0}, zb = {0,0,0,0};
#pragma unroll
    for (int kt = 0; kt < 3; ++kt) {
        const int arow = w * 16 + l16 + kt;
        const char* ab = As + arow * 512;
        const int swz = (arow & 7) << 4;
#pragma unroll
        for (int ec = 0; ec < 8; ++ec) {
            const bf16x8 af = *(const bf16x8*)(ab + ((ec * 64 + lg * 16) ^ swz));
            const int kc = kt * 8 + ec;
            za = mfma16(af, *(const bf16x8*)(Bs + (kc * 2) * 1024 + L * 16), za);
            zb = mfma16(af, *(const bf16x8*)(Bs + (kc * 2 + 1) * 1024 + L * 16), zb);
        }
    }
    const int p = ct * 16 + l16;
    const float cbA = conv_b[p], cbB = conv_b[p + 256];
#pragma unroll
    for (int j = 0; j < 4; ++j) {
        const int t = w * 16 + lg * 4 + j;
        const float v = za[j] + cbA, u = zb[j] + cbB;
        z_bf[(b * TT + t) * EE + p] = f2bf(v / (1.0f + __expf(-u)));
    }
}

// ---------------------------------------------------------------------------
// K2: h = z @ W^T + W_b + s.  grid (ct=16, b=16), block 256.
// Block: 64 t x 16 cols. z (32KB) + W slice (8KB) + s slice (2KB) in LDS.
// ---------------------------------------------------------------------------
__global__ __launch_bounds__(256) void k_h(
    const unsigned short* __restrict__ z_bf, const unsigned short* __restrict__ W_bf,
    const float* __restrict__ W_b, const unsigned short* __restrict__ s_bf,
    unsigned short* __restrict__ h_bf) {
    __shared__ __align__(16) char Zs[32768];
    __shared__ __align__(16) char Ws[8192];
    __shared__ unsigned short Ss[1024];
    const int ct = blockIdx.x, b = blockIdx.y;
    const int tid = threadIdx.x;
    const int w = tid >> 6, L = tid & 63, l16 = L & 15, lg = L >> 4;

#pragma unroll
    for (int it = 0; it < 8; ++it) {
        int unit = tid + it * 256;
        int row = unit >> 5, ch = unit & 31;
        u16x8 v = *(const u16x8*)(z_bf + (b * TT + row) * EE + ch * 8);
        *(u16x8*)(Zs + row * 512 + ((ch * 16) ^ ((row & 7) << 4))) = v;
    }
    {
        const int row = tid >> 4;
        const unsigned short* src = W_bf + (ct * 16 + row) * EE;
#pragma unroll
        for (int it = 0; it < 2; ++it) {
            int ch = (tid & 15) + it * 16;
            u16x8 v = *(const u16x8*)(src + ch * 8);
            *(u16x8*)(Ws + (ch >> 2) * 1024 + (ch & 3) * 256 + row * 16) = v;
        }
    }
    if (tid < 128) {
        int t = tid >> 1, part = tid & 1;
        *(u16x8*)(Ss + t * 16 + part * 8) =
            *(const u16x8*)(s_bf + (b * TT + t) * EE + ct * 16 + part * 8);
    }
    __syncthreads();

    f32x4 acc = {0,0,0,0};
    const int arow = w * 16 + l16;
#pragma unroll
    for (int kc = 0; kc < 8; ++kc) {
        const bf16x8 af = *(const bf16x8*)(Zs + arow * 512 + ((kc * 64 + lg * 16) ^ ((arow & 7) << 4)));
        acc = mfma16(af, *(const bf16x8*)(Ws + kc * 1024 + L * 16), acc);
    }
    const int c = ct * 16 + l16;
    const float wb = W_b[c];
#pragma unroll
    for (int j = 0; j < 4; ++j) {
        const int t = w * 16 + lg * 4 + j;
        h_bf[(b * TT + t) * EE + c] = f2bf(acc[j] + wb + bf2f(Ss[t * 16 + l16]));
    }
}

// ---------------------------------------------------------------------------
// K3: scores = h . dec^T.  grid (st=8, b=16), block 256.
// Block: 64 t x 64 s. h[b] (32KB) + dec slice (32KB) in LDS. scores f32 out.
// ---------------------------------------------------------------------------
__global__ __launch_bounds__(256) void k_scores(
    const unsigned short* __restrict__ h_bf, const unsigned short* __restrict__ dec_bf,
    float* __restrict__ scores) {
    __shared__ __align__(16) char Hs[32768];
    __shared__ __align__(16) char Ds[32768];
    const int st = blockIdx.x, b = blockIdx.y;
    const int tid = threadIdx.x;
    const int w = tid >> 6, L = tid & 63, l16 = L & 15, lg = L >> 4;

#pragma unroll
    for (int it = 0; it < 8; ++it) {
        int unit = tid + it * 256;
        int row = unit >> 5, ch = unit & 31;
        u16x8 v = *(const u16x8*)(h_bf + (b * TT + row) * EE + ch * 8);
        *(u16x8*)(Hs + row * 512 + ((ch * 16) ^ ((row & 7) << 4))) = v;
    }
    {
        const int ch = tid & 31, rowb = tid >> 5;
#pragma unroll
        for (int it = 0; it < 8; ++it) {
            int row = rowb + it * 8;
            u16x8 v = *(const u16x8*)(dec_bf + (b * HWXY + st * 64 + row) * EE + ch * 8);
            *(u16x8*)(Ds + ((ch >> 2) * 4 + (row >> 4)) * 1024 + (ch & 3) * 256 + (row & 15) * 16) = v;
        }
    }
    __syncthreads();

    f32x4 sc[4] = {{0,0,0,0},{0,0,0,0},{0,0,0,0},{0,0,0,0}};
    const int arow = w * 16 + l16;
#pragma unroll
    for (int kc = 0; kc < 8; ++kc) {
        const bf16x8 af = *(const bf16x8*)(Hs + arow * 512 + ((kc * 64 + lg * 16) ^ ((arow & 7) << 4)));
#pragma unroll
        for (int nf = 0; nf < 4; ++nf)
            sc[nf] = mfma16(af, *(const bf16x8*)(Ds + (kc * 4 + nf) * 1024 + L * 16), sc[nf]);
    }
#pragma unroll
    for (int nf = 0; nf < 4; ++nf)
#pragma unroll
        for (int j = 0; j < 4; ++j) {
            const int t = w * 16 + lg * 4 + j;
            scores[(b * TT + t) * HWXY + st * 64 + nf * 16 + l16] = sc[nf][j];
        }
}

// ---------------------------------------------------------------------------
// K4: row softmax over s=512 -> normalized p (bf16). grid 128, block 256.
// Block: 8 rows; each wave 2 rows (64 lanes x 8 f32).
// ---------------------------------------------------------------------------
__global__ __launch_bounds__(256) void k_softmax(
    const float* __restrict__ scores, unsigned short* __restrict__ p_bf) {
    const int bid = blockIdx.x;
    const int b = bid >> 3, tt = bid & 7;
    const int w = threadIdx.x >> 6, L = threadIdx.x & 63;
#pragma unroll
    for (int it = 0; it < 2; ++it) {
        const int row = b * TT + tt * 8 + w * 2 + it;
        const float* sp = scores + row * HWXY + L * 8;
        float4 v0 = *(const float4*)sp, v1 = *(const float4*)(sp + 4);
        float v[8] = {v0.x, v0.y, v0.z, v0.w, v1.x, v1.y, v1.z, v1.w};
        float m = v[0];
#pragma unroll
        for (int k = 1; k < 8; ++k) m = fmaxf(m, v[k]);
#pragma unroll
        for (int off = 32; off >= 1; off >>= 1) m = fmaxf(m, __shfl_xor(m, off));
        float p[8], sum = 0.f;
#pragma unroll
        for (int k = 0; k < 8; ++k) { p[k] = __expf(v[k] - m); sum += p[k]; }
#pragma unroll
        for (int off = 32; off >= 1; off >>= 1) sum += __shfl_xor(sum, off);
        const float inv = 1.0f / sum;
        u16x8 pk;
#pragma unroll
        for (int k = 0; k < 8; ++k) pk[k] = f2bf(p[k] * inv);
        *(u16x8*)(p_bf + row * HWXY + L * 8) = pk;
    }
}

// ---------------------------------------------------------------------------
// K5: a = p . res^T + z.  grid (et=8, b=16), block 256.
// Block: 64 t x 32 e, K=512. p[b] (64KB) + resT slice (32KB) + z slice (4KB).
// ---------------------------------------------------------------------------
__global__ __launch_bounds__(256) void k_attn(
    const unsigned short* __restrict__ p_bf, const unsigned short* __restrict__ resT,
    const unsigned short* __restrict__ z_bf, unsigned short* __restrict__ a_out) {
    __shared__ __align__(16) char Ps[65536];
    __shared__ __align__(16) char Bs[32768];
    __shared__ unsigned short Zr[2048];
    const int et = blockIdx.x, b = blockIdx.y;
    const int tid = threadIdx.x;
    const int w = tid >> 6, L = tid & 63, l16 = L & 15, lg = L >> 4;

    {
        const int ch = tid & 63, rowb = tid >> 6;
#pragma unroll
        for (int it = 0; it < 16; ++it) {
            int row = rowb + it * 4;
            u16x8 v = *(const u16x8*)(p_bf + (b * TT + row) * HWXY + ch * 8);
            *(u16x8*)(Ps + row * 1024 + ((ch * 16) ^ ((row & 7) << 4))) = v;
        }
#pragma unroll
        for (int it = 0; it < 8; ++it) {
            int row = rowb + it * 4;
            u16x8 v = *(const u16x8*)(resT + (b * EE + et * 32 + row) * HWXY + ch * 8);
            *(u16x8*)(Bs + ((ch >> 2) * 2 + (row >> 4)) * 1024 + (ch & 3) * 256 + (row & 15) * 16) = v;
        }
    }
    {
        int t = tid >> 2, part = tid & 3;
        *(u16x8*)(Zr + t * 32 + part * 8) =
            *(const u16x8*)(z_bf + (b * TT + t) * EE + et * 32 + part * 8);
    }
    __syncthreads();

    f32x4 c0 = {0,0,0,0}, c1 = {0,0,0,0};
    const int arow = w * 16 + l16;
#pragma unroll
    for (int kc = 0; kc < 16; ++kc) {
        const bf16x8 af = *(const bf16x8*)(Ps + arow * 1024 + ((kc * 64 + lg * 16) ^ ((arow & 7) << 4)));
        c0 = mfma16(af, *(const bf16x8*)(Bs + (kc * 2) * 1024 + L * 16), c0);
        c1 = mfma16(af, *(const bf16x8*)(Bs + (kc * 2 + 1) * 1024 + L * 16), c1);
    }
#pragma unroll
    for (int j = 0; j < 4; ++j) {
        const int t = w * 16 + lg * 4 + j;
        unsigned short* ap = a_out + (b * TT + t) * EE + et * 32;
        ap[l16]      = f2bf(c0[j] + bf2f(Zr[t * 32 + l16]));
        ap[l16 + 16] = f2bf(c1[j] + bf2f(Zr[t * 32 + 16 + l16]));
    }
}

// ---------------------------------------------------------------------------
// K6: logits = a @ Wo^T + Wo_b; log_softmax over V=128. grid (tt=4, b=16).
// Block: 16 t x 128 v. a tile (8KB) + Wo (64KB) in LDS.
// ---------------------------------------------------------------------------
__global__ __launch_bounds__(256) void k_logits(
    const unsigned short* __restrict__ a_bf, const unsigned short* __restrict__ Wo_bf,
    const float* __restrict__ Wo_b, float* __restrict__ out) {
    __shared__ __align__(16) char As[8192];
    __shared__ __align__(16) char Ws[65536];
    __shared__ float red_m[64], red_s[64];
    const int tt = blockIdx.x, b = blockIdx.y;
    const int tid = threadIdx.x;
    const int w = tid >> 6, L = tid & 63, l16 = L & 15, lg = L >> 4;

#pragma unroll
    for (int it = 0; it < 2; ++it) {
        int unit = tid + it * 256;
        int row = unit >> 5, ch = unit & 31;
        u16x8 v = *(const u16x8*)(a_bf + (b * TT + tt * 16 + row) * EE + ch * 8);
        *(u16x8*)(As + row * 512 + ((ch * 16) ^ ((row & 7) << 4))) = v;
    }
    {
        const int ch = tid & 31, rowb = tid >> 5;
#pragma unroll
        for (int it = 0; it < 16; ++it) {
            int row = rowb + it * 8;
            u16x8 v = *(const u16x8*)(Wo_bf + row * EE + ch * 8);
            *(u16x8*)(Ws + ((ch >> 2) * 8 + (row >> 4)) * 1024 + (ch & 3) * 256 + (row & 15) * 16) = v;
        }
    }
    __syncthreads();

    f32x4 l0 = {0,0,0,0}, l1 = {0,0,0,0};
#pragma unroll
    for (int kc = 0; kc < 8; ++kc) {
        const bf16x8 af = *(const bf16x8*)(As + l16 * 512 + ((kc * 64 + lg * 16) ^ ((l16 & 7) << 4)));
        l0 = mfma16(af, *(const bf16x8*)(Ws + (kc * 8 + w * 2) * 1024 + L * 16), l0);
        l1 = mfma16(af, *(const bf16x8*)(Ws + (kc * 8 + w * 2 + 1) * 1024 + L * 16), l1);
    }
    const int v0 = w * 32 + l16, v1 = v0 + 16;
    const float wb0 = Wo_b[v0], wb1 = Wo_b[v1];
    float lv0[4], lv1[4], mg[4];
#pragma unroll
    for (int j = 0; j < 4; ++j) {
        lv0[j] = l0[j] + wb0;
        lv1[j] = l1[j] + wb1;
        float m = fmaxf(lv0[j], lv1[j]);
#pragma unroll
        for (int off = 8; off >= 1; off >>= 1) m = fmaxf(m, __shfl_xor(m, off));
        if (l16 == 0) red_m[(lg * 4 + j) * 4 + w] = m;
    }
    __syncthreads();
#pragma unroll
    for (int j = 0; j < 4; ++j) {
        const int row = lg * 4 + j;
        float m = red_m[row * 4 + 0];
#pragma unroll
        for (int ww = 1; ww < 4; ++ww) m = fmaxf(m, red_m[row * 4 + ww]);
        mg[j] = m;
        float s = __expf(lv0[j] - m) + __expf(lv1[j] - m);
#pragma unroll
        for (int off = 8; off >= 1; off >>= 1) s += __shfl_xor(s, off);
        if (l16 == 0) red_s[row * 4 + w] = s;
    }
    __syncthreads();
#pragma unroll
    for (int j = 0; j < 4; ++j) {
        const int row = lg * 4 + j;
        float s = red_s[row * 4 + 0] + red_s[row * 4 + 1] + red_s[row * 4 + 2] + red_s[row * 4 + 3];
        const float lse = mg[j] + __logf(s);
        const int gt = b * TT + tt * 16 + row;
        out[gt * VV + v0] = lv0[j] - lse;
        out[gt * VV + v1] = lv1[j] - lse;
    }
}

// ---------------------------------------------------------------------------
extern "C" void kernel_launch(void* const* d_in, const int* in_sizes, int n_in,
                              void* d_out, int out_size, void* d_ws, size_t ws_size,
                              hipStream_t stream) {
    const float* enc    = (const float*)d_in[0];
    const float* dec    = (const float*)d_in[1];
    const int*   labels = (const int*)d_in[2];
    const float* embed  = (const float*)d_in[3];
    const float* conv_w = (const float*)d_in[4];
    const float* conv_b = (const float*)d_in[5];
    const float* W_w    = (const float*)d_in[6];
    const float* W_b    = (const float*)d_in[7];
    const float* Wo_w   = (const float*)d_in[8];
    const float* Wo_b   = (const float*)d_in[9];
    float* out = (float*)d_out;
    char* ws = (char*)d_ws;

    unsigned short* a0     = (unsigned short*)(ws + 0x000000);   // 512 KB
    unsigned short* a1     = (unsigned short*)(ws + 0x080000);   // 512 KB
    unsigned short* s_bf   = (unsigned short*)(ws + 0x100000);   // 512 KB
    unsigned short* dec_bf = (unsigned short*)(ws + 0x180000);   // 4 MB
    unsigned short* resT   = (unsigned short*)(ws + 0x580000);   // 4 MB
    unsigned short* convwT = (unsigned short*)(ws + 0x980000);   // 768 KB
    unsigned short* W_bf   = (unsigned short*)(ws + 0xA40000);   // 128 KB
    unsigned short* Wo_bf  = (unsigned short*)(ws + 0xA60000);   // 64 KB
    unsigned short* z_bf   = (unsigned short*)(ws + 0xA80000);   // 512 KB
    unsigned short* h_bf   = (unsigned short*)(ws + 0xB00000);   // 512 KB
    unsigned short* p_bf   = (unsigned short*)(ws + 0xB80000);   // 1 MB
    float*          scores = (float*)(ws + 0xC80000);            // 2 MB

    k_setup<<<784, 256, 0, stream>>>(enc, dec, labels, embed, conv_w, W_w, Wo_w,
                                     s_bf, a0, dec_bf, resT, convwT, W_bf, Wo_bf);

    unsigned short* ain = a0;
    unsigned short* aout = a1;
    for (int l = 0; l < 3; ++l) {
        k_conv<<<dim3(16, 16), 256, 0, stream>>>(ain, convwT, conv_b, z_bf);
        k_h<<<dim3(16, 16), 256, 0, stream>>>(z_bf, W_bf, W_b, s_bf, h_bf);
        k_scores<<<dim3(8, 16), 256, 0, stream>>>(h_bf, dec_bf, scores);
        k_softmax<<<128, 256, 0, stream>>>(scores, p_bf);
        k_attn<<<dim3(8, 16), 256, 0, stream>>>(p_bf, resT, z_bf, aout);
        unsigned short* tmp = ain; ain = aout; aout = tmp;
    }
    k_logits<<<dim3(4, 16), 256, 0, stream>>>(ain, Wo_bf, Wo_b, out);
}

// Round 8
// 81.235 us; speedup vs baseline: 1.8359x; 1.0698x over previous
//
#include <hip/hip_runtime.h>
#include <hip/hip_bf16.h>
#include <math.h>

#define BB 16
#define TT 64
#define HWXY 512
#define EE 256
#define VV 128

typedef __bf16 bf16x8 __attribute__((ext_vector_type(8)));
typedef unsigned short u16x8 __attribute__((ext_vector_type(8)));
typedef float f32x4 __attribute__((ext_vector_type(4)));

__device__ __forceinline__ f32x4 mfma16(bf16x8 a, bf16x8 b, f32x4 c) {
    return __builtin_amdgcn_mfma_f32_16x16x32_bf16(a, b, c, 0, 0, 0);
}

__device__ __forceinline__ unsigned short f2bf(float f) {
    union { float f; unsigned int i; } v; v.f = f;
    unsigned int x = v.i;
    return (unsigned short)((x + 0x7fffu + ((x >> 16) & 1u)) >> 16);  // RNE
}

__device__ __forceinline__ float bf2f(unsigned short u) {
    union { unsigned int i; float f; } v; v.i = ((unsigned int)u) << 16;
    return v.f;
}

__device__ __forceinline__ u16x8 pack8(float4 v0, float4 v1) {
    u16x8 o;
    o[0] = f2bf(v0.x); o[1] = f2bf(v0.y); o[2] = f2bf(v0.z); o[3] = f2bf(v0.w);
    o[4] = f2bf(v1.x); o[5] = f2bf(v1.y); o[6] = f2bf(v1.z); o[7] = f2bf(v1.w);
    return o;
}

// Async global->LDS DMA, 16B/lane. LDS dest must be wave-uniform; HW writes
// lane i at dest + i*16. Global src is per-lane (we pre-gather/swizzle there).
__device__ __forceinline__ void dma16(const void* g, void* l) {
    __builtin_amdgcn_global_load_lds(
        (const __attribute__((address_space(1))) void*)g,
        (__attribute__((address_space(3))) void*)l, 16, 0, 0);
}

#define VMWAIT0() do { asm volatile("s_waitcnt vmcnt(0)" ::: "memory"); \
                       __builtin_amdgcn_sched_barrier(0); } while (0)

// ---------------------------------------------------------------------------
// Setup: LDS-tiled transposes (resT, convwT) + vectorized elementwise
// ---------------------------------------------------------------------------
__global__ __launch_bounds__(256) void k_setup(
    const float* __restrict__ enc, const float* __restrict__ dec,
    const int* __restrict__ labels, const float* __restrict__ embed,
    const float* __restrict__ conv_w, const float* __restrict__ W_w,
    const float* __restrict__ Wo_w,
    unsigned short* __restrict__ s_bf, unsigned short* __restrict__ a_bf,
    unsigned short* __restrict__ dec_bf, unsigned short* __restrict__ resT,
    unsigned short* __restrict__ convwT, unsigned short* __restrict__ W_bf,
    unsigned short* __restrict__ Wo_bf) {
    __shared__ unsigned short tl[64][66];
    int bid = blockIdx.x;
    if (bid < 512) {
        const int b = bid >> 5, rem = bid & 31;
        const int s0 = (rem >> 2) << 6, e0 = (rem & 3) << 6;
#pragma unroll
        for (int it = 0; it < 16; ++it) {
            int lin = threadIdx.x + it * 256;
            int sl = lin >> 6, el = lin & 63;
            int src = (b * HWXY + s0 + sl) * EE + e0 + el;
            float dv = dec[src];
            dec_bf[src] = f2bf(dv);
            tl[sl][el] = f2bf(enc[src] + dv);
        }
        __syncthreads();
#pragma unroll
        for (int it = 0; it < 16; ++it) {
            int lin = threadIdx.x + it * 256;
            int el = lin >> 6, sl = lin & 63;
            resT[(b * EE + e0 + el) * HWXY + s0 + sl] = tl[sl][el];
        }
        return;
    }
    bid -= 512;
    if (bid < 96) {
        const int c0 = (bid >> 3) << 6, j0 = (bid & 7) << 6;
#pragma unroll
        for (int it = 0; it < 16; ++it) {
            int lin = threadIdx.x + it * 256;
            int cl = lin >> 6, jl = lin & 63;
            tl[cl][jl] = f2bf(conv_w[(c0 + cl) * 512 + j0 + jl]);
        }
        __syncthreads();
#pragma unroll
        for (int it = 0; it < 16; ++it) {
            int lin = threadIdx.x + it * 256;
            int jl = lin >> 6, cl = lin & 63;
            convwT[(j0 + jl) * 768 + c0 + cl] = tl[cl][jl];
        }
        return;
    }
    bid -= 96;
    int i8 = (bid * 256 + threadIdx.x) * 8;
    const int n1 = BB * TT * EE;
    const int n2 = EE * EE;
    if (i8 < n1) {
        int b = i8 >> 14, t = (i8 >> 8) & 63, e = i8 & 255;
        int lab = labels[b * TT + t];
        const float* ep = embed + lab * EE + e;
        float4 v0 = *(const float4*)ep, v1 = *(const float4*)(ep + 4);
        u16x8 p = pack8(v0, v1);
        *(u16x8*)(s_bf + i8) = p;
        *(u16x8*)(a_bf + i8) = p;
        return;
    }
    i8 -= n1;
    if (i8 < n2) {
        float4 v0 = *(const float4*)(W_w + i8), v1 = *(const float4*)(W_w + i8 + 4);
        *(u16x8*)(W_bf + i8) = pack8(v0, v1);
        return;
    }
    i8 -= n2;
    float4 v0 = *(const float4*)(Wo_w + i8), v1 = *(const float4*)(Wo_w + i8 + 4);
    *(u16x8*)(Wo_bf + i8) = pack8(v0, v1);
}

// ---------------------------------------------------------------------------
// K1: conv(K=3,E->2E)+GLU -> z. grid (ct=16, b=16), block 256.
// B-frags DMA'd in frag order; A halo staged manually (zero rows).
// ---------------------------------------------------------------------------
__global__ __launch_bounds__(256) void k_conv(
    const unsigned short* __restrict__ a_in, const unsigned short* __restrict__ convwT,
    const float* __restrict__ conv_b, unsigned short* __restrict__ z_bf) {
    __shared__ __align__(16) char As[33792];   // 66 rows x 512B, XOR-swizzled chunks
    __shared__ __align__(16) char Bs[49152];   // 48 slots x 1024B (slot = kc*2+half)
    const int ct = blockIdx.x, b = blockIdx.y;
    const int tid = threadIdx.x;
    const int w = tid >> 6, L = tid & 63, l16 = L & 15, lg = L >> 4;

#pragma unroll
    for (int i = 0; i < 12; ++i) {
        const int slot = w * 12 + i;           // 0..47
        const int kc = slot >> 1, half = slot & 1;
        dma16(convwT + (ct * 16 + l16 + half * 256) * 768 + kc * 32 + lg * 8,
              Bs + slot * 1024);
    }
#pragma unroll
    for (int i = 0; i < 9; ++i) {
        int unit = tid + i * 256;
        if (unit < 2112) {
            int row = unit >> 5, ch = unit & 31;
            int t = row - 1;
            u16x8 v = {0,0,0,0,0,0,0,0};
            if (t >= 0 && t < TT) v = *(const u16x8*)(a_in + (b * TT + t) * EE + ch * 8);
            *(u16x8*)(As + row * 512 + ((ch ^ (row & 7)) << 4)) = v;
        }
    }
    VMWAIT0();
    __syncthreads();

    f32x4 za = {0,0,0,0}, zb = {0,0,0,0};
#pragma unroll
    for (int kt = 0; kt < 3; ++kt) {
        const int arow = w * 16 + l16 + kt;
        const char* ab = As + arow * 512;
        const int swz = (arow & 7) << 4;
#pragma unroll
        for (int ec = 0; ec < 8; ++ec) {
            const bf16x8 af = *(const bf16x8*)(ab + ((ec * 64 + lg * 16) ^ swz));
            const int kc = kt * 8 + ec;
            za = mfma16(af, *(const bf16x8*)(Bs + (kc * 2) * 1024 + L * 16), za);
            zb = mfma16(af, *(const bf16x8*)(Bs + (kc * 2 + 1) * 1024 + L * 16), zb);
        }
    }
    const int p = ct * 16 + l16;
    const float cbA = conv_b[p], cbB = conv_b[p + 256];
#pragma unroll
    for (int j = 0; j < 4; ++j) {
        const int t = w * 16 + lg * 4 + j;
        const float v = za[j] + cbA, u = zb[j] + cbB;
        z_bf[(b * TT + t) * EE + p] = f2bf(v / (1.0f + __expf(-u)));
    }
}

// ---------------------------------------------------------------------------
// K2: h = z @ W^T + W_b + s. grid (ct=16, b=16), block 256. All-DMA staging.
// ---------------------------------------------------------------------------
__global__ __launch_bounds__(256) void k_h(
    const unsigned short* __restrict__ z_bf, const unsigned short* __restrict__ W_bf,
    const float* __restrict__ W_b, const unsigned short* __restrict__ s_bf,
    unsigned short* __restrict__ h_bf) {
    __shared__ __align__(16) char Zs[32768];   // 64 rows x 512B, swizzled
    __shared__ __align__(16) char Ws[8192];    // 8 slots x 1024B
    __shared__ unsigned short Ss[1024];
    const int ct = blockIdx.x, b = blockIdx.y;
    const int tid = threadIdx.x;
    const int w = tid >> 6, L = tid & 63, l16 = L & 15, lg = L >> 4;

#pragma unroll
    for (int i = 0; i < 8; ++i) {
        const int p = w * 8 + i;               // row pair 0..31
        const int row = p * 2 + (L >> 5);
        dma16(z_bf + (b * TT + row) * EE + (((L & 31) ^ (row & 7)) << 3), Zs + p * 1024);
    }
#pragma unroll
    for (int i = 0; i < 2; ++i) {
        const int kc = w * 2 + i;
        dma16(W_bf + (ct * 16 + l16) * EE + kc * 32 + lg * 8, Ws + kc * 1024);
    }
    if (tid < 128) {
        int t = tid >> 1, part = tid & 1;
        *(u16x8*)(Ss + t * 16 + part * 8) =
            *(const u16x8*)(s_bf + (b * TT + t) * EE + ct * 16 + part * 8);
    }
    VMWAIT0();
    __syncthreads();

    f32x4 acc = {0,0,0,0};
    const int arow = w * 16 + l16;
#pragma unroll
    for (int kc = 0; kc < 8; ++kc) {
        const bf16x8 af = *(const bf16x8*)(Zs + arow * 512 + ((kc * 64 + lg * 16) ^ ((arow & 7) << 4)));
        acc = mfma16(af, *(const bf16x8*)(Ws + kc * 1024 + L * 16), acc);
    }
    const int c = ct * 16 + l16;
    const float wb = W_b[c];
#pragma unroll
    for (int j = 0; j < 4; ++j) {
        const int t = w * 16 + lg * 4 + j;
        h_bf[(b * TT + t) * EE + c] = f2bf(acc[j] + wb + bf2f(Ss[t * 16 + l16]));
    }
}

// ---------------------------------------------------------------------------
// K3: scores tile + PARTIAL softmax. grid (st=8, b=16), block 256.
// Writes p_un = exp(sc - m_st) bf16 (plain [1024][512]) + per-(b,st,t) m,sum.
// ---------------------------------------------------------------------------
__global__ __launch_bounds__(256) void k_scores(
    const unsigned short* __restrict__ h_bf, const unsigned short* __restrict__ dec_bf,
    unsigned short* __restrict__ p_bf, float* __restrict__ m_part,
    float* __restrict__ s_part) {
    __shared__ __align__(16) char Hs[32768];
    __shared__ __align__(16) char Ds[32768];   // 32 slots (kc*4+nf)
    const int st = blockIdx.x, b = blockIdx.y;
    const int tid = threadIdx.x;
    const int w = tid >> 6, L = tid & 63, l16 = L & 15, lg = L >> 4;

#pragma unroll
    for (int i = 0; i < 8; ++i) {
        const int p = w * 8 + i;
        const int row = p * 2 + (L >> 5);
        dma16(h_bf + (b * TT + row) * EE + (((L & 31) ^ (row & 7)) << 3), Hs + p * 1024);
    }
#pragma unroll
    for (int i = 0; i < 8; ++i) {
        const int slot = w * 8 + i;            // kc*4 + nf
        const int kc = slot >> 2, nf = slot & 3;
        dma16(dec_bf + (b * HWXY + st * 64 + nf * 16 + l16) * EE + kc * 32 + lg * 8,
              Ds + slot * 1024);
    }
    VMWAIT0();
    __syncthreads();

    f32x4 sc[4] = {{0,0,0,0},{0,0,0,0},{0,0,0,0},{0,0,0,0}};
    const int arow = w * 16 + l16;
#pragma unroll
    for (int kc = 0; kc < 8; ++kc) {
        const bf16x8 af = *(const bf16x8*)(Hs + arow * 512 + ((kc * 64 + lg * 16) ^ ((arow & 7) << 4)));
#pragma unroll
        for (int nf = 0; nf < 4; ++nf)
            sc[nf] = mfma16(af, *(const bf16x8*)(Ds + (kc * 4 + nf) * 1024 + L * 16), sc[nf]);
    }
    // per-row (within this 64-col block): max + expsum partials
    float pm[4], ps[4];
#pragma unroll
    for (int j = 0; j < 4; ++j) {
        float m = fmaxf(fmaxf(sc[0][j], sc[1][j]), fmaxf(sc[2][j], sc[3][j]));
#pragma unroll
        for (int off = 8; off >= 1; off >>= 1) m = fmaxf(m, __shfl_xor(m, off));
        pm[j] = m;
        float s = 0.f;
#pragma unroll
        for (int nf = 0; nf < 4; ++nf) {
            const float pv = __expf(sc[nf][j] - m);
            sc[nf][j] = pv;
            s += pv;
        }
#pragma unroll
        for (int off = 8; off >= 1; off >>= 1) s += __shfl_xor(s, off);
        ps[j] = s;
    }
    if (l16 == 0) {
#pragma unroll
        for (int j = 0; j < 4; ++j) {
            const int t = w * 16 + lg * 4 + j;
            m_part[(b * 8 + st) * TT + t] = pm[j];
            s_part[(b * 8 + st) * TT + t] = ps[j];
        }
    }
#pragma unroll
    for (int nf = 0; nf < 4; ++nf)
#pragma unroll
        for (int j = 0; j < 4; ++j) {
            const int t = w * 16 + lg * 4 + j;
            p_bf[(b * TT + t) * HWXY + st * 64 + nf * 16 + l16] = f2bf(sc[nf][j]);
        }
}

// ---------------------------------------------------------------------------
// K5: a = softmax-normalized(p_un) . res^T + z. grid (et=8, b=16), block 256.
// Normalization folded in as 8 per-st sub-accumulations scaled by corr.
// ---------------------------------------------------------------------------
__global__ __launch_bounds__(256) void k_attn(
    const unsigned short* __restrict__ p_bf, const unsigned short* __restrict__ resT,
    const unsigned short* __restrict__ z_bf, const float* __restrict__ m_part,
    const float* __restrict__ s_part, unsigned short* __restrict__ a_out) {
    __shared__ __align__(16) char Ps[65536];   // 64 rows x 1024B, swizzled
    __shared__ __align__(16) char Bs[32768];   // 32 slots (kc*2+nf)
    __shared__ unsigned short Zr[2048];
    __shared__ float mp[512], sp[512];
    const int et = blockIdx.x, b = blockIdx.y;
    const int tid = threadIdx.x;
    const int w = tid >> 6, L = tid & 63, l16 = L & 15, lg = L >> 4;

#pragma unroll
    for (int i = 0; i < 16; ++i) {
        const int r = w * 16 + i;
        dma16(p_bf + (b * TT + r) * HWXY + ((L ^ (r & 7)) << 3), Ps + r * 1024);
    }
#pragma unroll
    for (int i = 0; i < 8; ++i) {
        const int slot = w * 8 + i;            // kc*2 + nf
        const int kc = slot >> 1, nf = slot & 1;
        dma16(resT + (b * EE + et * 32 + nf * 16 + l16) * HWXY + kc * 32 + lg * 8,
              Bs + slot * 1024);
    }
    {
        int t = tid >> 2, part = tid & 3;
        *(u16x8*)(Zr + t * 32 + part * 8) =
            *(const u16x8*)(z_bf + (b * TT + t) * EE + et * 32 + part * 8);
        mp[tid] = m_part[b * 512 + tid];
        mp[tid + 256] = m_part[b * 512 + tid + 256];
        sp[tid] = s_part[b * 512 + tid];
        sp[tid + 256] = s_part[b * 512 + tid + 256];
    }
    VMWAIT0();
    __syncthreads();

    // global normalization factors: corr[j][st] = exp(m_st - m_g) / S_g
    float corr[4][8];
#pragma unroll
    for (int j = 0; j < 4; ++j) {
        const int t = w * 16 + lg * 4 + j;
        float mg = mp[t];
#pragma unroll
        for (int st = 1; st < 8; ++st) mg = fmaxf(mg, mp[st * 64 + t]);
        float S = 0.f;
#pragma unroll
        for (int st = 0; st < 8; ++st) {
            const float c = __expf(mp[st * 64 + t] - mg);
            corr[j][st] = c;
            S += sp[st * 64 + t] * c;
        }
        const float is = 1.0f / S;
#pragma unroll
        for (int st = 0; st < 8; ++st) corr[j][st] *= is;
    }

    f32x4 ca0 = {0,0,0,0}, ca1 = {0,0,0,0};
    const int arow = w * 16 + l16;
#pragma unroll
    for (int st = 0; st < 8; ++st) {
        f32x4 t0 = {0,0,0,0}, t1 = {0,0,0,0};
#pragma unroll
        for (int q = 0; q < 2; ++q) {
            const int kc = st * 2 + q;
            const bf16x8 af = *(const bf16x8*)(
                Ps + arow * 1024 + (((kc * 4 + lg) ^ (arow & 7)) << 4));
            t0 = mfma16(af, *(const bf16x8*)(Bs + (kc * 2) * 1024 + L * 16), t0);
            t1 = mfma16(af, *(const bf16x8*)(Bs + (kc * 2 + 1) * 1024 + L * 16), t1);
        }
#pragma unroll
        for (int j = 0; j < 4; ++j) {
            ca0[j] += t0[j] * corr[j][st];
            ca1[j] += t1[j] * corr[j][st];
        }
    }
#pragma unroll
    for (int j = 0; j < 4; ++j) {
        const int t = w * 16 + lg * 4 + j;
        unsigned short* ap = a_out + (b * TT + t) * EE + et * 32;
        ap[l16]      = f2bf(ca0[j] + bf2f(Zr[t * 32 + l16]));
        ap[l16 + 16] = f2bf(ca1[j] + bf2f(Zr[t * 32 + 16 + l16]));
    }
}

// ---------------------------------------------------------------------------
// K6: logits + log_softmax. grid (tt=4, b=16), block 256. All-DMA staging.
// ---------------------------------------------------------------------------
__global__ __launch_bounds__(256) void k_logits(
    const unsigned short* __restrict__ a_bf, const unsigned short* __restrict__ Wo_bf,
    const float* __restrict__ Wo_b, float* __restrict__ out) {
    __shared__ __align__(16) char As[8192];    // 16 rows x 512B, swizzled
    __shared__ __align__(16) char Ws[65536];   // 64 slots (kc*8+vg)
    __shared__ float red_m[64], red_s[64];
    const int tt = blockIdx.x, b = blockIdx.y;
    const int tid = threadIdx.x;
    const int w = tid >> 6, L = tid & 63, l16 = L & 15, lg = L >> 4;

#pragma unroll
    for (int i = 0; i < 2; ++i) {
        const int p = w * 2 + i;               // row pair 0..7
        const int row = p * 2 + (L >> 5);
        dma16(a_bf + (b * TT + tt * 16 + row) * EE + (((L & 31) ^ (row & 7)) << 3),
              As + p * 1024);
    }
#pragma unroll
    for (int i = 0; i < 16; ++i) {
        const int slot = w * 16 + i;           // kc*8 + vg
        const int kc = slot >> 3, vg = slot & 7;
        dma16(Wo_bf + (vg * 16 + l16) * EE + kc * 32 + lg * 8, Ws + slot * 1024);
    }
    VMWAIT0();
    __syncthreads();

    f32x4 l0 = {0,0,0,0}, l1 = {0,0,0,0};
#pragma unroll
    for (int kc = 0; kc < 8; ++kc) {
        const bf16x8 af = *(const bf16x8*)(As + l16 * 512 + ((kc * 64 + lg * 16) ^ ((l16 & 7) << 4)));
        l0 = mfma16(af, *(const bf16x8*)(Ws + (kc * 8 + w * 2) * 1024 + L * 16), l0);
        l1 = mfma16(af, *(const bf16x8*)(Ws + (kc * 8 + w * 2 + 1) * 1024 + L * 16), l1);
    }
    const int v0 = w * 32 + l16, v1 = v0 + 16;
    const float wb0 = Wo_b[v0], wb1 = Wo_b[v1];
    float lv0[4], lv1[4], mg[4];
#pragma unroll
    for (int j = 0; j < 4; ++j) {
        lv0[j] = l0[j] + wb0;
        lv1[j] = l1[j] + wb1;
        float m = fmaxf(lv0[j], lv1[j]);
#pragma unroll
        for (int off = 8; off >= 1; off >>= 1) m = fmaxf(m, __shfl_xor(m, off));
        if (l16 == 0) red_m[(lg * 4 + j) * 4 + w] = m;
    }
    __syncthreads();
#pragma unroll
    for (int j = 0; j < 4; ++j) {
        const int row = lg * 4 + j;
        float m = red_m[row * 4 + 0];
#pragma unroll
        for (int ww = 1; ww < 4; ++ww) m = fmaxf(m, red_m[row * 4 + ww]);
        mg[j] = m;
        float s = __expf(lv0[j] - m) + __expf(lv1[j] - m);
#pragma unroll
        for (int off = 8; off >= 1; off >>= 1) s += __shfl_xor(s, off);
        if (l16 == 0) red_s[row * 4 + w] = s;
    }
    __syncthreads();
#pragma unroll
    for (int j = 0; j < 4; ++j) {
        const int row = lg * 4 + j;
        float s = red_s[row * 4 + 0] + red_s[row * 4 + 1] + red_s[row * 4 + 2] + red_s[row * 4 + 3];
        const float lse = mg[j] + __logf(s);
        const int gt = b * TT + tt * 16 + row;
        out[gt * VV + v0] = lv0[j] - lse;
        out[gt * VV + v1] = lv1[j] - lse;
    }
}

// ---------------------------------------------------------------------------
extern "C" void kernel_launch(void* const* d_in, const int* in_sizes, int n_in,
                              void* d_out, int out_size, void* d_ws, size_t ws_size,
                              hipStream_t stream) {
    const float* enc    = (const float*)d_in[0];
    const float* dec    = (const float*)d_in[1];
    const int*   labels = (const int*)d_in[2];
    const float* embed  = (const float*)d_in[3];
    const float* conv_w = (const float*)d_in[4];
    const float* conv_b = (const float*)d_in[5];
    const float* W_w    = (const float*)d_in[6];
    const float* W_b    = (const float*)d_in[7];
    const float* Wo_w   = (const float*)d_in[8];
    const float* Wo_b   = (const float*)d_in[9];
    float* out = (float*)d_out;
    char* ws = (char*)d_ws;

    unsigned short* a0     = (unsigned short*)(ws + 0x000000);   // 512 KB
    unsigned short* a1     = (unsigned short*)(ws + 0x080000);   // 512 KB
    unsigned short* s_bf   = (unsigned short*)(ws + 0x100000);   // 512 KB
    unsigned short* dec_bf = (unsigned short*)(ws + 0x180000);   // 4 MB
    unsigned short* resT   = (unsigned short*)(ws + 0x580000);   // 4 MB
    unsigned short* convwT = (unsigned short*)(ws + 0x980000);   // 768 KB
    unsigned short* W_bf   = (unsigned short*)(ws + 0xA40000);   // 128 KB
    unsigned short* Wo_bf  = (unsigned short*)(ws + 0xA60000);   // 64 KB
    unsigned short* z_bf   = (unsigned short*)(ws + 0xA80000);   // 512 KB
    unsigned short* h_bf   = (unsigned short*)(ws + 0xB00000);   // 512 KB
    unsigned short* p_bf   = (unsigned short*)(ws + 0xB80000);   // 1 MB
    float*          m_part = (float*)(ws + 0xC80000);            // 32 KB
    float*          s_part = (float*)(ws + 0xC88000);            // 32 KB

    k_setup<<<784, 256, 0, stream>>>(enc, dec, labels, embed, conv_w, W_w, Wo_w,
                                     s_bf, a0, dec_bf, resT, convwT, W_bf, Wo_bf);

    unsigned short* ain = a0;
    unsigned short* aout = a1;
    for (int l = 0; l < 3; ++l) {
        k_conv<<<dim3(16, 16), 256, 0, stream>>>(ain, convwT, conv_b, z_bf);
        k_h<<<dim3(16, 16), 256, 0, stream>>>(z_bf, W_bf, W_b, s_bf, h_bf);
        k_scores<<<dim3(8, 16), 256, 0, stream>>>(h_bf, dec_bf, p_bf, m_part, s_part);
        k_attn<<<dim3(8, 16), 256, 0, stream>>>(p_bf, resT, z_bf, m_part, s_part, aout);
        unsigned short* tmp = ain; ain = aout; aout = tmp;
    }
    k_logits<<<dim3(4, 16), 256, 0, stream>>>(ain, Wo_bf, Wo_b, out);
}

// Round 9
// 77.769 us; speedup vs baseline: 1.9177x; 1.0446x over previous
//
#include <hip/hip_runtime.h>
#include <hip/hip_bf16.h>
#include <math.h>

#define BB 16
#define TT 64
#define HWXY 512
#define EE 256
#define VV 128

typedef __bf16 bf16x8 __attribute__((ext_vector_type(8)));
typedef unsigned short u16x8 __attribute__((ext_vector_type(8)));
typedef float f32x4 __attribute__((ext_vector_type(4)));

__device__ __forceinline__ f32x4 mfma16(bf16x8 a, bf16x8 b, f32x4 c) {
    return __builtin_amdgcn_mfma_f32_16x16x32_bf16(a, b, c, 0, 0, 0);
}

__device__ __forceinline__ unsigned short f2bf(float f) {
    union { float f; unsigned int i; } v; v.f = f;
    unsigned int x = v.i;
    return (unsigned short)((x + 0x7fffu + ((x >> 16) & 1u)) >> 16);  // RNE
}

__device__ __forceinline__ float bf2f(unsigned short u) {
    union { unsigned int i; float f; } v; v.i = ((unsigned int)u) << 16;
    return v.f;
}

__device__ __forceinline__ u16x8 pack8(float4 v0, float4 v1) {
    u16x8 o;
    o[0] = f2bf(v0.x); o[1] = f2bf(v0.y); o[2] = f2bf(v0.z); o[3] = f2bf(v0.w);
    o[4] = f2bf(v1.x); o[5] = f2bf(v1.y); o[6] = f2bf(v1.z); o[7] = f2bf(v1.w);
    return o;
}

// Async global->LDS DMA, 16B/lane. LDS dest wave-uniform; lane i lands at
// dest + i*16. Per-lane global src carries any gather/swizzle.
__device__ __forceinline__ void dma16(const void* g, void* l) {
    __builtin_amdgcn_global_load_lds(
        (const __attribute__((address_space(1))) void*)g,
        (__attribute__((address_space(3))) void*)l, 16, 0, 0);
}

#define VMWAIT0() do { asm volatile("s_waitcnt vmcnt(0)" ::: "memory"); \
                       __builtin_amdgcn_sched_barrier(0); } while (0)

// ---------------------------------------------------------------------------
// Setup: LDS-tiled transposes (resT, convwT, W^T) + vectorized elementwise
// grid 768: [0,512) resT, [512,608) convwT, [608,624) WT, [624,768) misc
// ---------------------------------------------------------------------------
__global__ __launch_bounds__(256) void k_setup(
    const float* __restrict__ enc, const float* __restrict__ dec,
    const int* __restrict__ labels, const float* __restrict__ embed,
    const float* __restrict__ conv_w, const float* __restrict__ W_w,
    const float* __restrict__ Wo_w,
    unsigned short* __restrict__ s_bf, unsigned short* __restrict__ a_bf,
    unsigned short* __restrict__ dec_bf, unsigned short* __restrict__ resT,
    unsigned short* __restrict__ convwT, unsigned short* __restrict__ WT,
    unsigned short* __restrict__ Wo_bf) {
    __shared__ unsigned short tl[64][66];
    int bid = blockIdx.x;
    if (bid < 512) {
        const int b = bid >> 5, rem = bid & 31;
        const int s0 = (rem >> 2) << 6, e0 = (rem & 3) << 6;
#pragma unroll
        for (int it = 0; it < 16; ++it) {
            int lin = threadIdx.x + it * 256;
            int sl = lin >> 6, el = lin & 63;
            int src = (b * HWXY + s0 + sl) * EE + e0 + el;
            float dv = dec[src];
            dec_bf[src] = f2bf(dv);
            tl[sl][el] = f2bf(enc[src] + dv);
        }
        __syncthreads();
#pragma unroll
        for (int it = 0; it < 16; ++it) {
            int lin = threadIdx.x + it * 256;
            int el = lin >> 6, sl = lin & 63;
            resT[(b * EE + e0 + el) * HWXY + s0 + sl] = tl[sl][el];
        }
        return;
    }
    bid -= 512;
    if (bid < 96) {
        const int c0 = (bid >> 3) << 6, j0 = (bid & 7) << 6;
#pragma unroll
        for (int it = 0; it < 16; ++it) {
            int lin = threadIdx.x + it * 256;
            int cl = lin >> 6, jl = lin & 63;
            tl[cl][jl] = f2bf(conv_w[(c0 + cl) * 512 + j0 + jl]);
        }
        __syncthreads();
#pragma unroll
        for (int it = 0; it < 16; ++it) {
            int lin = threadIdx.x + it * 256;
            int jl = lin >> 6, cl = lin & 63;
            convwT[(j0 + jl) * 768 + c0 + cl] = tl[cl][jl];
        }
        return;
    }
    bid -= 96;
    if (bid < 16) {
        // WT[e][e'] = W_w[e'][e]
        const int c0 = (bid >> 2) << 6, j0 = (bid & 3) << 6;  // c0: e' rows, j0: e cols
#pragma unroll
        for (int it = 0; it < 16; ++it) {
            int lin = threadIdx.x + it * 256;
            int cl = lin >> 6, jl = lin & 63;
            tl[cl][jl] = f2bf(W_w[(c0 + cl) * 256 + j0 + jl]);
        }
        __syncthreads();
#pragma unroll
        for (int it = 0; it < 16; ++it) {
            int lin = threadIdx.x + it * 256;
            int el = lin >> 6, pl = lin & 63;
            WT[(j0 + el) * 256 + c0 + pl] = tl[pl][el];
        }
        return;
    }
    bid -= 16;
    int i8 = (bid * 256 + threadIdx.x) * 8;
    const int n1 = BB * TT * EE;
    if (i8 < n1) {
        int b = i8 >> 14, t = (i8 >> 8) & 63, e = i8 & 255;
        int lab = labels[b * TT + t];
        const float* ep = embed + lab * EE + e;
        float4 v0 = *(const float4*)ep, v1 = *(const float4*)(ep + 4);
        u16x8 p = pack8(v0, v1);
        *(u16x8*)(s_bf + i8) = p;
        *(u16x8*)(a_bf + i8) = p;
        return;
    }
    i8 -= n1;
    float4 v0 = *(const float4*)(Wo_w + i8), v1 = *(const float4*)(Wo_w + i8 + 4);
    *(u16x8*)(Wo_bf + i8) = pack8(v0, v1);
}

// ---------------------------------------------------------------------------
// k_precomp (runs once): grid 384.
//  bid<256: G[b,s,e] = sum_e' dec[b,s,e'] WT[e][e']   (b, st of 64 s, et of 128 e)
//  else:    base[b,t,s] = sum_e' (s[t,e']+W_b[e']) dec[b,s,e']  (b, st of 64 s)
// ---------------------------------------------------------------------------
__global__ __launch_bounds__(256) void k_precomp(
    const unsigned short* __restrict__ dec_bf, const unsigned short* __restrict__ WT,
    const unsigned short* __restrict__ s_bf, const float* __restrict__ W_b,
    unsigned short* __restrict__ G, float* __restrict__ base_g) {
    __shared__ __align__(16) char smem[98304];
    char* const As = smem;            // 64 rows x 512B swizzled
    char* const Bs = smem + 32768;    // up to 64 slots x 1KB
    const int tid = threadIdx.x;
    const int w = tid >> 6, L = tid & 63, l16 = L & 15, lg = L >> 4;
    int bid = blockIdx.x;

    if (bid < 256) {
        const int b = bid >> 4, st = (bid >> 1) & 7, et = bid & 1;
        // A: dec rows (64 x 256), pre-swizzled DMA
#pragma unroll
        for (int i = 0; i < 8; ++i) {
            const int p = w * 8 + i;
            const int r = 2 * p + (L >> 5);
            dma16(dec_bf + (b * HWXY + st * 64 + r) * EE + (((L & 31) ^ (r & 7)) << 3),
                  As + p * 1024);
        }
        // B: WT rows [et*128 .. +128), slots kc*8+nf
#pragma unroll
        for (int i = 0; i < 16; ++i) {
            const int slot = w * 16 + i;
            const int kc = slot >> 3, nf = slot & 7;
            dma16(WT + (et * 128 + nf * 16 + l16) * EE + kc * 32 + lg * 8,
                  Bs + slot * 1024);
        }
        VMWAIT0();
        __syncthreads();
        f32x4 acc[4][2] = {{{0,0,0,0},{0,0,0,0}},{{0,0,0,0},{0,0,0,0}},
                           {{0,0,0,0},{0,0,0,0}},{{0,0,0,0},{0,0,0,0}}};
#pragma unroll
        for (int kc = 0; kc < 8; ++kc) {
#pragma unroll
            for (int m = 0; m < 4; ++m) {
                const int arow = m * 16 + l16;
                const bf16x8 af = *(const bf16x8*)(
                    As + arow * 512 + (((kc * 4 + lg) ^ (arow & 7)) << 4));
                acc[m][0] = mfma16(af, *(const bf16x8*)(Bs + (kc * 8 + w * 2) * 1024 + L * 16), acc[m][0]);
                acc[m][1] = mfma16(af, *(const bf16x8*)(Bs + (kc * 8 + w * 2 + 1) * 1024 + L * 16), acc[m][1]);
            }
        }
#pragma unroll
        for (int m = 0; m < 4; ++m)
#pragma unroll
            for (int nf = 0; nf < 2; ++nf)
#pragma unroll
                for (int j = 0; j < 4; ++j) {
                    const int s = st * 64 + m * 16 + lg * 4 + j;
                    const int e = et * 128 + w * 32 + nf * 16 + l16;
                    G[(b * HWXY + s) * EE + e] = f2bf(acc[m][nf][j]);
                }
    } else {
        bid -= 256;
        const int b = bid >> 3, st = bid & 7;
        // A: (s + W_b) rows, staged manually swizzled
#pragma unroll
        for (int it = 0; it < 8; ++it) {
            int unit = tid + it * 256;
            int row = unit >> 5, ch = unit & 31;
            u16x8 v = *(const u16x8*)(s_bf + (b * TT + row) * EE + ch * 8);
            u16x8 o;
#pragma unroll
            for (int k = 0; k < 8; ++k) o[k] = f2bf(bf2f(v[k]) + W_b[ch * 8 + k]);
            *(u16x8*)(As + row * 512 + ((ch ^ (row & 7)) << 4)) = o;
        }
        // B: dec slice, slots kc*4+nf
#pragma unroll
        for (int i = 0; i < 8; ++i) {
            const int slot = w * 8 + i;
            const int kc = slot >> 2, nf = slot & 3;
            dma16(dec_bf + (b * HWXY + st * 64 + nf * 16 + l16) * EE + kc * 32 + lg * 8,
                  Bs + slot * 1024);
        }
        VMWAIT0();
        __syncthreads();
        f32x4 acc[4] = {{0,0,0,0},{0,0,0,0},{0,0,0,0},{0,0,0,0}};
        const int arow = w * 16 + l16;
#pragma unroll
        for (int kc = 0; kc < 8; ++kc) {
            const bf16x8 af = *(const bf16x8*)(
                As + arow * 512 + (((kc * 4 + lg) ^ (arow & 7)) << 4));
#pragma unroll
            for (int nf = 0; nf < 4; ++nf)
                acc[nf] = mfma16(af, *(const bf16x8*)(Bs + (kc * 4 + nf) * 1024 + L * 16), acc[nf]);
        }
#pragma unroll
        for (int nf = 0; nf < 4; ++nf)
#pragma unroll
            for (int j = 0; j < 4; ++j) {
                const int t = w * 16 + lg * 4 + j;
                base_g[(b * TT + t) * HWXY + st * 64 + nf * 16 + l16] = acc[nf][j];
            }
    }
}

// ---------------------------------------------------------------------------
// K1: conv(K=3,E->2E)+GLU -> z. grid (ct=16, b=16), block 256. All-DMA.
// ---------------------------------------------------------------------------
__global__ __launch_bounds__(256) void k_conv(
    const unsigned short* __restrict__ a_in, const unsigned short* __restrict__ convwT,
    const float* __restrict__ conv_b, unsigned short* __restrict__ z_bf) {
    __shared__ __align__(16) char As[33792];   // 66 rows x 512B, swizzled
    __shared__ __align__(16) char Bs[49152];   // 48 slots x 1KB
    const int ct = blockIdx.x, b = blockIdx.y;
    const int tid = threadIdx.x;
    const int w = tid >> 6, L = tid & 63, l16 = L & 15, lg = L >> 4;

#pragma unroll
    for (int i = 0; i < 12; ++i) {
        const int slot = w * 12 + i;
        const int kc = slot >> 1, half = slot & 1;
        dma16(convwT + (ct * 16 + l16 + half * 256) * 768 + kc * 32 + lg * 8,
              Bs + slot * 1024);
    }
    // A rows 1..64 (t=0..63) via pre-swizzled DMA; rows 0,65 zeroed manually
#pragma unroll
    for (int i = 0; i < 8; ++i) {
        const int p = w * 8 + i;
        const int r = 1 + 2 * p + (L >> 5);
        dma16(a_in + (b * TT + r - 1) * EE + (((L & 31) ^ (r & 7)) << 3),
              As + 512 + p * 1024);
    }
    if (tid < 64) {
        char* dst = (tid < 32) ? (As + tid * 16) : (As + 65 * 512 + (tid - 32) * 16);
        *(u16x8*)dst = (u16x8){0,0,0,0,0,0,0,0};
    }
    VMWAIT0();
    __syncthreads();

    f32x4 za = {0,0,0,0}, zb = {0,0,0,0};
#pragma unroll
    for (int kt = 0; kt < 3; ++kt) {
        const int arow = w * 16 + l16 + kt;
        const char* ab = As + arow * 512;
        const int swz = (arow & 7) << 4;
#pragma unroll
        for (int ec = 0; ec < 8; ++ec) {
            const bf16x8 af = *(const bf16x8*)(ab + ((ec * 64 + lg * 16) ^ swz));
            const int kc = kt * 8 + ec;
            za = mfma16(af, *(const bf16x8*)(Bs + (kc * 2) * 1024 + L * 16), za);
            zb = mfma16(af, *(const bf16x8*)(Bs + (kc * 2 + 1) * 1024 + L * 16), zb);
        }
    }
    const int p = ct * 16 + l16;
    const float cbA = conv_b[p], cbB = conv_b[p + 256];
#pragma unroll
    for (int j = 0; j < 4; ++j) {
        const int t = w * 16 + lg * 4 + j;
        const float v = za[j] + cbA, u = zb[j] + cbB;
        z_bf[(b * TT + t) * EE + p] = f2bf(v / (1.0f + __expf(-u)));
    }
}

// ---------------------------------------------------------------------------
// K3: scores = z@G^T + base, partial softmax per 32-col block.
// grid (st=16, b=16), block 256. Writes p_un bf16 + m/s partials.
// ---------------------------------------------------------------------------
__global__ __launch_bounds__(256) void k_scores(
    const unsigned short* __restrict__ z_bf, const unsigned short* __restrict__ G,
    const float* __restrict__ base_g, unsigned short* __restrict__ p_bf,
    float* __restrict__ m_part, float* __restrict__ s_part) {
    __shared__ __align__(16) char Zs[32768];   // 64 rows x 512B swizzled
    __shared__ __align__(16) char Gs[16384];   // 16 slots (kc*2+nf)
    __shared__ float basel[64 * 36];           // padded f32 tile
    const int st = blockIdx.x, b = blockIdx.y;
    const int tid = threadIdx.x;
    const int w = tid >> 6, L = tid & 63, l16 = L & 15, lg = L >> 4;

#pragma unroll
    for (int i = 0; i < 8; ++i) {
        const int p = w * 8 + i;
        const int r = 2 * p + (L >> 5);
        dma16(z_bf + (b * TT + r) * EE + (((L & 31) ^ (r & 7)) << 3), Zs + p * 1024);
    }
#pragma unroll
    for (int i = 0; i < 4; ++i) {
        const int slot = w * 4 + i;            // kc*2 + nf
        const int kc = slot >> 1, nf = slot & 1;
        dma16(G + (b * HWXY + st * 32 + nf * 16 + l16) * EE + kc * 32 + lg * 8,
              Gs + slot * 1024);
    }
    {
        const int row = tid >> 2, c0 = (tid & 3) * 8;
        const float* src = base_g + (b * TT + row) * HWXY + st * 32 + c0;
        float4 v0 = *(const float4*)src, v1 = *(const float4*)(src + 4);
        *(float4*)(basel + row * 36 + c0) = v0;
        *(float4*)(basel + row * 36 + c0 + 4) = v1;
    }
    VMWAIT0();
    __syncthreads();

    f32x4 sc[2] = {{0,0,0,0},{0,0,0,0}};
    const int arow = w * 16 + l16;
#pragma unroll
    for (int kc = 0; kc < 8; ++kc) {
        const bf16x8 af = *(const bf16x8*)(
            Zs + arow * 512 + (((kc * 4 + lg) ^ (arow & 7)) << 4));
        sc[0] = mfma16(af, *(const bf16x8*)(Gs + (kc * 2) * 1024 + L * 16), sc[0]);
        sc[1] = mfma16(af, *(const bf16x8*)(Gs + (kc * 2 + 1) * 1024 + L * 16), sc[1]);
    }
    // + base, then partial softmax over the 32 cols
    float pm[4], ps[4];
#pragma unroll
    for (int j = 0; j < 4; ++j) {
        const int row = w * 16 + lg * 4 + j;
        sc[0][j] += basel[row * 36 + l16];
        sc[1][j] += basel[row * 36 + 16 + l16];
        float m = fmaxf(sc[0][j], sc[1][j]);
#pragma unroll
        for (int off = 8; off >= 1; off >>= 1) m = fmaxf(m, __shfl_xor(m, off));
        pm[j] = m;
        const float p0 = __expf(sc[0][j] - m);
        const float p1 = __expf(sc[1][j] - m);
        sc[0][j] = p0; sc[1][j] = p1;
        float s = p0 + p1;
#pragma unroll
        for (int off = 8; off >= 1; off >>= 1) s += __shfl_xor(s, off);
        ps[j] = s;
    }
    if (l16 == 0) {
#pragma unroll
        for (int j = 0; j < 4; ++j) {
            const int t = w * 16 + lg * 4 + j;
            m_part[(b * 16 + st) * TT + t] = pm[j];
            s_part[(b * 16 + st) * TT + t] = ps[j];
        }
    }
#pragma unroll
    for (int nf = 0; nf < 2; ++nf)
#pragma unroll
        for (int j = 0; j < 4; ++j) {
            const int t = w * 16 + lg * 4 + j;
            p_bf[(b * TT + t) * HWXY + st * 32 + nf * 16 + l16] = f2bf(sc[nf][j]);
        }
}

// ---------------------------------------------------------------------------
// K5: a = softmax-normalized(p_un) . res^T + z. grid (et=8, tt=2, b=16).
// Block: 32 t x 32 e; 16 sub-accumulations scaled by corr.
// ---------------------------------------------------------------------------
__global__ __launch_bounds__(256) void k_attn(
    const unsigned short* __restrict__ p_bf, const unsigned short* __restrict__ resT,
    const unsigned short* __restrict__ z_bf, const float* __restrict__ m_part,
    const float* __restrict__ s_part, unsigned short* __restrict__ a_out) {
    __shared__ __align__(16) char Ps[32768];   // 32 rows x 1KB swizzled
    __shared__ __align__(16) char Bs[32768];   // 32 slots (kc*2+nf)
    __shared__ unsigned short Zr[1024];        // 32 x 32
    __shared__ float mp[512], sp[512];         // [st16][t32]
    const int et = blockIdx.x, tt = blockIdx.y, b = blockIdx.z;
    const int tid = threadIdx.x;
    const int w = tid >> 6, L = tid & 63, l16 = L & 15, lg = L >> 4;

#pragma unroll
    for (int i = 0; i < 8; ++i) {
        const int r = w * 8 + i;               // local row 0..31
        dma16(p_bf + (b * TT + tt * 32 + r) * HWXY + ((L ^ (r & 7)) << 3), Ps + r * 1024);
    }
#pragma unroll
    for (int i = 0; i < 8; ++i) {
        const int slot = w * 8 + i;            // kc*2 + nf
        const int kc = slot >> 1, nf = slot & 1;
        dma16(resT + (b * EE + et * 32 + nf * 16 + l16) * HWXY + kc * 32 + lg * 8,
              Bs + slot * 1024);
    }
    {
        if (tid < 128) {
            const int t = tid >> 2, part = tid & 3;
            *(u16x8*)(Zr + t * 32 + part * 8) =
                *(const u16x8*)(z_bf + (b * TT + tt * 32 + t) * EE + et * 32 + part * 8);
        }
        const int stl = tid >> 5, tl = tid & 31;
        mp[tid] = m_part[(b * 16 + stl) * TT + tt * 32 + tl];
        sp[tid] = s_part[(b * 16 + stl) * TT + tt * 32 + tl];
        mp[tid + 256] = m_part[(b * 16 + stl + 8) * TT + tt * 32 + tl];
        sp[tid + 256] = s_part[(b * 16 + stl + 8) * TT + tt * 32 + tl];
    }
    VMWAIT0();
    __syncthreads();

    const int mg = w >> 1, nh = w & 1;
    // corr[j][st] = exp(m_st - m_g)/S_g for this thread's rows
    float corr[4][16];
#pragma unroll
    for (int j = 0; j < 4; ++j) {
        const int row = mg * 16 + lg * 4 + j;
        float mgl = mp[row];
#pragma unroll
        for (int s = 1; s < 16; ++s) mgl = fmaxf(mgl, mp[s * 32 + row]);
        float S = 0.f;
#pragma unroll
        for (int s = 0; s < 16; ++s) {
            const float c = __expf(mp[s * 32 + row] - mgl);
            corr[j][s] = c;
            S += sp[s * 32 + row] * c;
        }
        const float is = 1.0f / S;
#pragma unroll
        for (int s = 0; s < 16; ++s) corr[j][s] *= is;
    }

    f32x4 ca = {0,0,0,0};
    const int arow = mg * 16 + l16;
#pragma unroll
    for (int st = 0; st < 16; ++st) {
        const bf16x8 af = *(const bf16x8*)(
            Ps + arow * 1024 + (((st * 4 + lg) ^ (arow & 7)) << 4));
        f32x4 t0 = mfma16(af, *(const bf16x8*)(Bs + (st * 2 + nh) * 1024 + L * 16),
                          (f32x4){0,0,0,0});
#pragma unroll
        for (int j = 0; j < 4; ++j) ca[j] += t0[j] * corr[j][st];
    }
#pragma unroll
    for (int j = 0; j < 4; ++j) {
        const int row = mg * 16 + lg * 4 + j;
        const int t = tt * 32 + row;
        a_out[(b * TT + t) * EE + et * 32 + nh * 16 + l16] =
            f2bf(ca[j] + bf2f(Zr[row * 32 + nh * 16 + l16]));
    }
}

// ---------------------------------------------------------------------------
// K6: logits + log_softmax. grid (tt=4, b=16), block 256. All-DMA staging.
// ---------------------------------------------------------------------------
__global__ __launch_bounds__(256) void k_logits(
    const unsigned short* __restrict__ a_bf, const unsigned short* __restrict__ Wo_bf,
    const float* __restrict__ Wo_b, float* __restrict__ out) {
    __shared__ __align__(16) char As[8192];
    __shared__ __align__(16) char Ws[65536];
    __shared__ float red_m[64], red_s[64];
    const int tt = blockIdx.x, b = blockIdx.y;
    const int tid = threadIdx.x;
    const int w = tid >> 6, L = tid & 63, l16 = L & 15, lg = L >> 4;

#pragma unroll
    for (int i = 0; i < 2; ++i) {
        const int p = w * 2 + i;
        const int row = p * 2 + (L >> 5);
        dma16(a_bf + (b * TT + tt * 16 + row) * EE + (((L & 31) ^ (row & 7)) << 3),
              As + p * 1024);
    }
#pragma unroll
    for (int i = 0; i < 16; ++i) {
        const int slot = w * 16 + i;
        const int kc = slot >> 3, vg = slot & 7;
        dma16(Wo_bf + (vg * 16 + l16) * EE + kc * 32 + lg * 8, Ws + slot * 1024);
    }
    VMWAIT0();
    __syncthreads();

    f32x4 l0 = {0,0,0,0}, l1 = {0,0,0,0};
#pragma unroll
    for (int kc = 0; kc < 8; ++kc) {
        const bf16x8 af = *(const bf16x8*)(As + l16 * 512 + ((kc * 64 + lg * 16) ^ ((l16 & 7) << 4)));
        l0 = mfma16(af, *(const bf16x8*)(Ws + (kc * 8 + w * 2) * 1024 + L * 16), l0);
        l1 = mfma16(af, *(const bf16x8*)(Ws + (kc * 8 + w * 2 + 1) * 1024 + L * 16), l1);
    }
    const int v0 = w * 32 + l16, v1 = v0 + 16;
    const float wb0 = Wo_b[v0], wb1 = Wo_b[v1];
    float lv0[4], lv1[4], mg[4];
#pragma unroll
    for (int j = 0; j < 4; ++j) {
        lv0[j] = l0[j] + wb0;
        lv1[j] = l1[j] + wb1;
        float m = fmaxf(lv0[j], lv1[j]);
#pragma unroll
        for (int off = 8; off >= 1; off >>= 1) m = fmaxf(m, __shfl_xor(m, off));
        if (l16 == 0) red_m[(lg * 4 + j) * 4 + w] = m;
    }
    __syncthreads();
#pragma unroll
    for (int j = 0; j < 4; ++j) {
        const int row = lg * 4 + j;
        float m = red_m[row * 4 + 0];
#pragma unroll
        for (int ww = 1; ww < 4; ++ww) m = fmaxf(m, red_m[row * 4 + ww]);
        mg[j] = m;
        float s = __expf(lv0[j] - m) + __expf(lv1[j] - m);
#pragma unroll
        for (int off = 8; off >= 1; off >>= 1) s += __shfl_xor(s, off);
        if (l16 == 0) red_s[row * 4 + w] = s;
    }
    __syncthreads();
#pragma unroll
    for (int j = 0; j < 4; ++j) {
        const int row = lg * 4 + j;
        float s = red_s[row * 4 + 0] + red_s[row * 4 + 1] + red_s[row * 4 + 2] + red_s[row * 4 + 3];
        const float lse = mg[j] + __logf(s);
        const int gt = b * TT + tt * 16 + row;
        out[gt * VV + v0] = lv0[j] - lse;
        out[gt * VV + v1] = lv1[j] - lse;
    }
}

// ---------------------------------------------------------------------------
extern "C" void kernel_launch(void* const* d_in, const int* in_sizes, int n_in,
                              void* d_out, int out_size, void* d_ws, size_t ws_size,
                              hipStream_t stream) {
    const float* enc    = (const float*)d_in[0];
    const float* dec    = (const float*)d_in[1];
    const int*   labels = (const int*)d_in[2];
    const float* embed  = (const float*)d_in[3];
    const float* conv_w = (const float*)d_in[4];
    const float* conv_b = (const float*)d_in[5];
    const float* W_w    = (const float*)d_in[6];
    const float* W_b    = (const float*)d_in[7];
    const float* Wo_w   = (const float*)d_in[8];
    const float* Wo_b   = (const float*)d_in[9];
    float* out = (float*)d_out;
    char* ws = (char*)d_ws;

    unsigned short* a0     = (unsigned short*)(ws + 0x000000);   // 512 KB
    unsigned short* a1     = (unsigned short*)(ws + 0x080000);   // 512 KB
    unsigned short* s_bf   = (unsigned short*)(ws + 0x100000);   // 512 KB
    unsigned short* dec_bf = (unsigned short*)(ws + 0x180000);   // 4 MB
    unsigned short* resT   = (unsigned short*)(ws + 0x580000);   // 4 MB
    unsigned short* convwT = (unsigned short*)(ws + 0x980000);   // 768 KB
    unsigned short* WT     = (unsigned short*)(ws + 0xA40000);   // 128 KB
    unsigned short* Wo_bf  = (unsigned short*)(ws + 0xA60000);   // 64 KB
    unsigned short* z_bf   = (unsigned short*)(ws + 0xA80000);   // 512 KB
    unsigned short* p_bf   = (unsigned short*)(ws + 0xB00000);   // 1 MB
    float*          m_part = (float*)(ws + 0xC00000);            // 64 KB
    float*          s_part = (float*)(ws + 0xC10000);            // 64 KB
    float*          base_g = (float*)(ws + 0xC20000);            // 2 MB
    unsigned short* G      = (unsigned short*)(ws + 0xE20000);   // 4 MB

    k_setup<<<768, 256, 0, stream>>>(enc, dec, labels, embed, conv_w, W_w, Wo_w,
                                     s_bf, a0, dec_bf, resT, convwT, WT, Wo_bf);
    k_precomp<<<384, 256, 0, stream>>>(dec_bf, WT, s_bf, W_b, G, base_g);

    unsigned short* ain = a0;
    unsigned short* aout = a1;
    for (int l = 0; l < 3; ++l) {
        k_conv<<<dim3(16, 16), 256, 0, stream>>>(ain, convwT, conv_b, z_bf);
        k_scores<<<dim3(16, 16), 256, 0, stream>>>(z_bf, G, base_g, p_bf, m_part, s_part);
        k_attn<<<dim3(8, 2, 16), 256, 0, stream>>>(p_bf, resT, z_bf, m_part, s_part, aout);
        unsigned short* tmp = ain; ain = aout; aout = tmp;
    }
    k_logits<<<dim3(4, 16), 256, 0, stream>>>(ain, Wo_bf, Wo_b, out);
}